// Round 3
// baseline (892.910 us; speedup 1.0000x reference)
//
#include <hip/hip_runtime.h>
#include <hip/hip_bf16.h>
#include <hip/hip_fp16.h>

#define QN    50
#define NWAY  5
#define NPAIR 250
#define MM    196
#define KMM   980
#define DD    640
#define KT    31     // 31 k-tiles of 32 cover 992 >= 980
#define MT    7      // 7 m-tiles of 32 cover 224 >= 196
#define NITER 5

#define L2M 7.6147098441152083f   // log2(196)
#define L2K 9.9366379390935392f   // log2(980)

typedef __attribute__((ext_vector_type(8)))  short short8;
typedef __attribute__((ext_vector_type(16))) float f32x16;

#define EXP2F(x) __builtin_exp2f(x)
#define LOG2F(x) __builtin_log2f(x)

__device__ __forceinline__ short bf16bits(float f) {
  __hip_bfloat16 h = __float2bfloat16(f);
  return *reinterpret_cast<short*>(&h);
}

// ---------------- GEMM: cost[m][k] fp16 + fused v1 (column logsumexp, u0=0) ----
__global__ __launch_bounds__(512, 2)
void gemm_kernel(const float* __restrict__ qt, const float* __restrict__ st,
                 const float* __restrict__ var, const float* __restrict__ epsr,
                 __half* __restrict__ cost, float* __restrict__ vpot)
{
  __shared__ __align__(16) float w_lds[DD];
  __shared__ float red_s;

  const int tid  = threadIdx.x;
  const int wave = tid >> 6;
  const int lane = tid & 63;
  const int l31  = lane & 31;
  const int lh   = lane >> 5;

  const int pair   = blockIdx.x >> 2;
  const int kgroup = blockIdx.x & 3;
  const int qi = pair / NWAY;
  const int wi = pair % NWAY;

  const float eps = logf(1.0f + expf(epsr[0])) + 1e-4f;
  const float C2  = 1.4426950408889634f / eps;   // logK2 = (sim-1)*C2

  // ---- per-dim weights ----
  float psum = 0.f;
  for (int d = tid; d < DD; d += 512) {
    float inv = 1.0f / (var[wi * DD + d] + 0.01f);
    w_lds[d] = inv;
    psum += inv;
  }
  #pragma unroll
  for (int s = 32; s; s >>= 1) psum += __shfl_xor(psum, s);
  if (tid == 0) red_s = 0.f;
  __syncthreads();
  if (lane == 0) atomicAdd(&red_s, psum);
  __syncthreads();
  const float wscale = (float)DD / fmaxf(red_s, 1e-6f);
  for (int d = tid; d < DD; d += 512) w_lds[d] *= wscale;
  __syncthreads();

  const int ktile = kgroup * 8 + wave;
  if (ktile >= KT) return;

  const float* qbase = qt + (size_t)qi * MM * DD;
  const float* sbase = st + (size_t)wi * KMM * DD;
  __half* cbase = cost + (size_t)pair * (MM * KMM);

  const int k0 = ktile * 32;
  const int kcol = k0 + l31;
  const float* srow = sbase + (size_t)min(k0 + l31, KMM - 1) * DD + lh * 8;

  f32x16 acc[MT];
  #pragma unroll
  for (int t = 0; t < MT; ++t)
    #pragma unroll
    for (int e = 0; e < 16; ++e) acc[t][e] = 0.f;

  for (int ds = 0; ds < DD / 16; ++ds) {
    const int d0 = ds * 16 + lh * 8;
    float4 w0 = *reinterpret_cast<const float4*>(w_lds + d0);
    float4 w1 = *reinterpret_cast<const float4*>(w_lds + d0 + 4);
    float4 s0 = *reinterpret_cast<const float4*>(srow + ds * 16);
    float4 s1 = *reinterpret_cast<const float4*>(srow + ds * 16 + 4);
    short8 b;
    b[0] = bf16bits(s0.x * w0.x); b[1] = bf16bits(s0.y * w0.y);
    b[2] = bf16bits(s0.z * w0.z); b[3] = bf16bits(s0.w * w0.w);
    b[4] = bf16bits(s1.x * w1.x); b[5] = bf16bits(s1.y * w1.y);
    b[6] = bf16bits(s1.z * w1.z); b[7] = bf16bits(s1.w * w1.w);
    #pragma unroll
    for (int mt = 0; mt < MT; ++mt) {
      const int mr = mt * 32 + l31;
      const float* qrow = qbase + (size_t)min(mr, MM - 1) * DD + d0;
      float4 a0 = *reinterpret_cast<const float4*>(qrow);
      float4 a1 = *reinterpret_cast<const float4*>(qrow + 4);
      short8 a;
      a[0] = bf16bits(a0.x); a[1] = bf16bits(a0.y);
      a[2] = bf16bits(a0.z); a[3] = bf16bits(a0.w);
      a[4] = bf16bits(a1.x); a[5] = bf16bits(a1.y);
      a[6] = bf16bits(a1.z); a[7] = bf16bits(a1.w);
      acc[mt] = __builtin_amdgcn_mfma_f32_32x32x16_bf16(a, b, acc[mt], 0, 0, 0);
    }
  }

  if (kcol >= KMM) return;  // tile 30, lanes 20..31: nothing to write

  // epilogue: store fp16 cost + column sum (u0 = 0)  [C/D: col=l31, row=(r&3)+8*(r>>2)+4*lh]
  float csum = 0.f;
  #pragma unroll
  for (int mt = 0; mt < MT; ++mt) {
    #pragma unroll
    for (int r = 0; r < 16; ++r) {
      const int mrow = mt * 32 + (r & 3) + 8 * (r >> 2) + 4 * lh;
      if (mrow < MM) {
        const float val = (acc[mt][r] - 1.0f) * C2;
        cbase[(size_t)mrow * KMM + kcol] = __float2half(val);
        csum += EXP2F(val);
      }
    }
  }
  csum += __shfl_xor(csum, 32);
  if (lh == 0)
    vpot[(size_t)pair * KMM + kcol] = -L2K - LOG2F(csum);
}

// ---------------- u-pass: wave per row, v in registers; FIN fuses OT ----------
template<bool FIN>
__global__ __launch_bounds__(256)
void u_kernel(const __half* __restrict__ cost, const float* __restrict__ vpot,
              float* __restrict__ upot, const float* __restrict__ epsr,
              const float* __restrict__ taur, float* __restrict__ outp)
{
  const int tid  = threadIdx.x;
  const int wave = tid >> 6;
  const int lane = tid & 63;
  const int pair   = blockIdx.x / 7;
  const int mchunk = blockIdx.x % 7;

  const __half* cbase = cost + (size_t)pair * (MM * KMM);
  const float*  vp    = vpot + (size_t)pair * KMM;

  float4 vv[4];
  #pragma unroll
  for (int j = 0; j < 4; ++j) {
    const int k = 4 * lane + 256 * j;
    vv[j] = (k < KMM) ? *reinterpret_cast<const float4*>(vp + k)
                      : make_float4(0.f, 0.f, 0.f, 0.f);
  }

  float C2 = 0.f, itau = 0.f;
  if (FIN) {
    const float eps = logf(1.0f + expf(epsr[0])) + 1e-4f;
    C2 = 1.4426950408889634f / eps;
    itau = 1.0f / (logf(1.0f + expf(taur[0])) + 0.01f);
  }

  #pragma unroll
  for (int r = 0; r < 7; ++r) {
    const int m = mchunk * 28 + wave * 7 + r;
    const __half* rp = cbase + (size_t)m * KMM;
    float A = 0.f, B = 0.f;
    #pragma unroll
    for (int j = 0; j < 4; ++j) {
      const int k = 4 * lane + 256 * j;
      if (k < KMM) {
        uint2 raw = *reinterpret_cast<const uint2*>(rp + k);
        __half2 h01 = *reinterpret_cast<const __half2*>(&raw.x);
        __half2 h23 = *reinterpret_cast<const __half2*>(&raw.y);
        float2 f01 = __half22float2(h01);
        float2 f23 = __half22float2(h23);
        float e0 = EXP2F(f01.x + vv[j].x);
        float e1 = EXP2F(f01.y + vv[j].y);
        float e2 = EXP2F(f23.x + vv[j].z);
        float e3 = EXP2F(f23.y + vv[j].w);
        A += (e0 + e1) + (e2 + e3);
        if (FIN) B += e0 * f01.x + e1 * f01.y + e2 * f23.x + e3 * f23.y;
      }
    }
    #pragma unroll
    for (int s = 32; s; s >>= 1) {
      A += __shfl_xor(A, s);
      if (FIN) B += __shfl_xor(B, s);
    }
    if (lane == 0) {
      if (FIN) {
        // row OT contribution: -(-B/(MM*C2*A)) / tau accumulated into out
        atomicAdd(outp + pair, B * itau / ((float)MM * C2 * A));
      } else {
        upot[(size_t)pair * MM + m] = -L2M - LOG2F(A);
      }
    }
  }
}

// ---------------- v-pass: thread per 2 columns, u in LDS ----------------------
__global__ __launch_bounds__(128)
void v_kernel(const __half* __restrict__ cost, const float* __restrict__ upot,
              float* __restrict__ vpot)
{
  __shared__ float u_lds[MM];
  const int tid = threadIdx.x;
  const int pair   = blockIdx.x >> 2;
  const int kchunk = blockIdx.x & 3;

  const __half* cbase = cost + (size_t)pair * (MM * KMM);
  for (int i = tid; i < MM; i += 128) u_lds[i] = upot[(size_t)pair * MM + i];
  __syncthreads();

  const int kc = kchunk * 256 + 2 * tid;
  if (kc >= KMM) return;
  const __half* cp = cbase + kc;
  float Sa = 0.f, Sb = 0.f;
  #pragma unroll 4
  for (int m = 0; m < MM; ++m) {
    __half2 hv = *reinterpret_cast<const __half2*>(cp + (size_t)m * KMM);
    float2 f = __half22float2(hv);
    const float u = u_lds[m];
    Sa += EXP2F(f.x + u);
    Sb += EXP2F(f.y + u);
  }
  vpot[(size_t)pair * KMM + kc]     = -L2K - LOG2F(Sa);
  vpot[(size_t)pair * KMM + kc + 1] = -L2K - LOG2F(Sb);   // kc<=978 -> kc+1<=979 ok
}

extern "C" void kernel_launch(void* const* d_in, const int* in_sizes, int n_in,
                              void* d_out, int out_size, void* d_ws, size_t ws_size,
                              hipStream_t stream) {
  const float* qt  = (const float*)d_in[0];
  const float* st  = (const float*)d_in[1];
  const float* var = (const float*)d_in[2];
  const float* er  = (const float*)d_in[3];
  const float* tr  = (const float*)d_in[4];
  float* out = (float*)d_out;

  // ws layout (97,216,000 B total — proven-safe bound from round 2):
  //   cost fp16 : 250*196*980*2 = 96,040,000
  //   upot  f32 : 250*196*4    =    196,000
  //   vpot  f32 : 250*980*4    =    980,000
  char* ws = (char*)d_ws;
  __half* cost = (__half*)ws;
  float*  upot = (float*)(ws + 96040000);
  float*  vpot = (float*)(ws + 96040000 + 196000);

  hipMemsetAsync(out, 0, NPAIR * sizeof(float), stream);   // OT accumulators
  gemm_kernel<<<NPAIR * 4, 512, 0, stream>>>(qt, st, var, er, cost, vpot);
  for (int it = 0; it < NITER; ++it) {
    if (it > 0)
      v_kernel<<<NPAIR * 4, 128, 0, stream>>>(cost, upot, vpot);
    if (it < NITER - 1)
      u_kernel<false><<<NPAIR * 7, 256, 0, stream>>>(cost, vpot, upot, er, tr, out);
    else
      u_kernel<true ><<<NPAIR * 7, 256, 0, stream>>>(cost, vpot, upot, er, tr, out);
  }
}

// Round 4
// 536.092 us; speedup vs baseline: 1.6656x; 1.6656x over previous
//
#include <hip/hip_runtime.h>
#include <hip/hip_bf16.h>
#include <hip/hip_fp16.h>

#define QN    50
#define NWAY  5
#define NPAIR 250
#define MM    196
#define KMM   980
#define DD    640
#define NITER 5

#define L2M 7.6147098441152083f   // log2(196)
#define L2K 9.9366379390935392f   // log2(980)

typedef __attribute__((ext_vector_type(8)))  short short8;
typedef __attribute__((ext_vector_type(16))) float f32x16;

#define EXP2F(x) __builtin_exp2f(x)
#define LOG2F(x) __builtin_log2f(x)

__device__ __forceinline__ short bf16bits(float f) {
  __hip_bfloat16 h = __float2bfloat16(f);
  return *reinterpret_cast<short*>(&h);
}

// ---------------- tiled GEMM: cost[m][k] fp16 + fused colsum (v1 raw) --------
// 128x128 tile, BK=64, 4 waves as 2x2 of 64x64. LDS XOR-swizzle (slot^=row&7)
// so fragment ds_read_b128 is ~conflict-free instead of 32-way.
__global__ __launch_bounds__(256, 2)
void gemm_kernel(const float* __restrict__ qt, const float* __restrict__ st,
                 const float* __restrict__ var, const float* __restrict__ epsr,
                 __half* __restrict__ cost, float* __restrict__ colsum)
{
  __shared__ __align__(16) unsigned short Ash[128 * 64];
  __shared__ __align__(16) unsigned short Bsh[128 * 64];
  __shared__ __align__(16) float w_lds[DD];
  __shared__ float cs_lds[128];
  __shared__ float red_s;

  const int tid  = threadIdx.x;
  const int wv   = tid >> 6;
  const int lane = tid & 63;
  const int l31  = lane & 31;
  const int lh   = lane >> 5;
  const int wm   = wv >> 1;        // wave m-half
  const int wn   = wv & 1;         // wave n-half

  const int bid  = blockIdx.x;
  const int pair = bid >> 4;
  const int mt_  = (bid >> 3) & 1; // m-tile 0/1
  const int nt_  = bid & 7;        // n-tile 0..7
  const int qi = pair / NWAY, wi = pair % NWAY;
  const int m0 = mt_ * 128, n0 = nt_ * 128;

  const float eps = logf(1.0f + expf(epsr[0])) + 1e-4f;
  const float C2  = 1.4426950408889634f / eps;

  // ---- per-dim weights into LDS ----
  float psum = 0.f;
  for (int d = tid; d < DD; d += 256) {
    float inv = 1.0f / (var[wi * DD + d] + 0.01f);
    w_lds[d] = inv; psum += inv;
  }
  #pragma unroll
  for (int s = 32; s; s >>= 1) psum += __shfl_xor(psum, s);
  if (tid == 0) red_s = 0.f;
  if (tid < 128) cs_lds[tid] = 0.f;
  __syncthreads();
  if (lane == 0) atomicAdd(&red_s, psum);
  __syncthreads();
  const float wsc = (float)DD / fmaxf(red_s, 1e-6f);
  for (int d = tid; d < DD; d += 256) w_lds[d] *= wsc;
  __syncthreads();

  const float* qb = qt + (size_t)qi * MM * DD;
  const float* sb = st + (size_t)wi * KMM * DD;

  f32x16 acc[2][2];
  #pragma unroll
  for (int i = 0; i < 2; ++i)
    #pragma unroll
    for (int j = 0; j < 2; ++j)
      #pragma unroll
      for (int e = 0; e < 16; ++e) acc[i][j][e] = 0.f;

  const int srow = tid >> 3;   // 0..31 (row within 32-row group)
  const int sslt = tid & 7;    // 16B slot 0..7 within a 128B row

  for (int ks = 0; ks < 10; ++ks) {
    const int kd = ks * 64 + sslt * 8;
    // ---- stage A,B (reg-staged: coalesced f32 loads, cvt, swizzled ds_write)
    #pragma unroll
    for (int i = 0; i < 4; ++i) {
      const int r = i * 32 + srow;
      const int wslt = (sslt ^ (r & 7)) * 8;
      {
        const int gr = min(m0 + r, MM - 1);
        const float* src = qb + (size_t)gr * DD + kd;
        float4 f0 = *reinterpret_cast<const float4*>(src);
        float4 f1 = *reinterpret_cast<const float4*>(src + 4);
        short8 pk;
        pk[0] = bf16bits(f0.x); pk[1] = bf16bits(f0.y);
        pk[2] = bf16bits(f0.z); pk[3] = bf16bits(f0.w);
        pk[4] = bf16bits(f1.x); pk[5] = bf16bits(f1.y);
        pk[6] = bf16bits(f1.z); pk[7] = bf16bits(f1.w);
        *reinterpret_cast<short8*>(&Ash[r * 64 + wslt]) = pk;
      }
      {
        const int gr = min(n0 + r, KMM - 1);
        const float* src = sb + (size_t)gr * DD + kd;
        const float* wp  = w_lds + kd;
        float4 f0 = *reinterpret_cast<const float4*>(src);
        float4 f1 = *reinterpret_cast<const float4*>(src + 4);
        float4 w0 = *reinterpret_cast<const float4*>(wp);
        float4 w1 = *reinterpret_cast<const float4*>(wp + 4);
        short8 pk;
        pk[0] = bf16bits(f0.x * w0.x); pk[1] = bf16bits(f0.y * w0.y);
        pk[2] = bf16bits(f0.z * w0.z); pk[3] = bf16bits(f0.w * w0.w);
        pk[4] = bf16bits(f1.x * w1.x); pk[5] = bf16bits(f1.y * w1.y);
        pk[6] = bf16bits(f1.z * w1.z); pk[7] = bf16bits(f1.w * w1.w);
        *reinterpret_cast<short8*>(&Bsh[r * 64 + wslt]) = pk;
      }
    }
    __syncthreads();
    // ---- compute: 4 k-steps of 16, 2x2 MFMA 32x32x16 ----
    #pragma unroll
    for (int kk = 0; kk < 4; ++kk) {
      const int ph = ((kk * 2 + lh) ^ (l31 & 7)) * 8;   // row&7 == l31&7
      short8 a0 = *reinterpret_cast<short8*>(&Ash[(wm * 64      + l31) * 64 + ph]);
      short8 a1 = *reinterpret_cast<short8*>(&Ash[(wm * 64 + 32 + l31) * 64 + ph]);
      short8 b0 = *reinterpret_cast<short8*>(&Bsh[(wn * 64      + l31) * 64 + ph]);
      short8 b1 = *reinterpret_cast<short8*>(&Bsh[(wn * 64 + 32 + l31) * 64 + ph]);
      acc[0][0] = __builtin_amdgcn_mfma_f32_32x32x16_bf16(a0, b0, acc[0][0], 0, 0, 0);
      acc[0][1] = __builtin_amdgcn_mfma_f32_32x32x16_bf16(a0, b1, acc[0][1], 0, 0, 0);
      acc[1][0] = __builtin_amdgcn_mfma_f32_32x32x16_bf16(a1, b0, acc[1][0], 0, 0, 0);
      acc[1][1] = __builtin_amdgcn_mfma_f32_32x32x16_bf16(a1, b1, acc[1][1], 0, 0, 0);
    }
    __syncthreads();
  }

  // ---- epilogue: fp16 store + per-column exp2 partial sums (u0 = 0) ----
  __half* cb = cost + (size_t)pair * MM * KMM;
  #pragma unroll
  for (int nt = 0; nt < 2; ++nt) {
    const int ncol = n0 + wn * 64 + nt * 32 + l31;
    float part = 0.f;
    #pragma unroll
    for (int mt = 0; mt < 2; ++mt) {
      #pragma unroll
      for (int r = 0; r < 16; ++r) {
        const int mrow = m0 + wm * 64 + mt * 32 + (r & 3) + 8 * (r >> 2) + 4 * lh;
        if (mrow < MM && ncol < KMM) {
          const float val = (acc[mt][nt][r] - 1.0f) * C2;
          cb[(size_t)mrow * KMM + ncol] = __float2half(val);
          part += EXP2F(val);
        }
      }
    }
    atomicAdd(&cs_lds[wn * 64 + nt * 32 + l31], part);
  }
  __syncthreads();
  if (tid < 128 && n0 + tid < KMM)
    atomicAdd(&colsum[(size_t)pair * KMM + n0 + tid], cs_lds[tid]);
}

// ---------------- finish v1: vpot = -L2K - log2(colsum), in place ------------
__global__ __launch_bounds__(256)
void vfin_kernel(float* __restrict__ vpot)
{
  const int i = blockIdx.x * 256 + threadIdx.x;
  if (i < NPAIR * KMM) vpot[i] = -L2K - LOG2F(vpot[i]);
}

// ---------------- u-pass: wave per row, v in registers; FIN fuses OT ---------
template<bool FIN>
__global__ __launch_bounds__(256)
void u_kernel(const __half* __restrict__ cost, const float* __restrict__ vpot,
              float* __restrict__ upot, const float* __restrict__ epsr,
              const float* __restrict__ taur, float* __restrict__ outp)
{
  const int tid  = threadIdx.x;
  const int wave = tid >> 6;
  const int lane = tid & 63;
  const int pair   = blockIdx.x / 7;
  const int mchunk = blockIdx.x % 7;

  const __half* cbase = cost + (size_t)pair * (MM * KMM);
  const float*  vp    = vpot + (size_t)pair * KMM;

  float4 vv[4];
  #pragma unroll
  for (int j = 0; j < 4; ++j) {
    const int k = 4 * lane + 256 * j;
    vv[j] = (k < KMM) ? *reinterpret_cast<const float4*>(vp + k)
                      : make_float4(0.f, 0.f, 0.f, 0.f);
  }

  float C2 = 0.f, itau = 0.f;
  if (FIN) {
    const float eps = logf(1.0f + expf(epsr[0])) + 1e-4f;
    C2 = 1.4426950408889634f / eps;
    itau = 1.0f / (logf(1.0f + expf(taur[0])) + 0.01f);
  }

  #pragma unroll
  for (int r = 0; r < 7; ++r) {
    const int m = mchunk * 28 + wave * 7 + r;
    const __half* rp = cbase + (size_t)m * KMM;
    float A = 0.f, B = 0.f;
    #pragma unroll
    for (int j = 0; j < 4; ++j) {
      const int k = 4 * lane + 256 * j;
      if (k < KMM) {
        uint2 raw = *reinterpret_cast<const uint2*>(rp + k);
        __half2 h01 = *reinterpret_cast<const __half2*>(&raw.x);
        __half2 h23 = *reinterpret_cast<const __half2*>(&raw.y);
        float2 f01 = __half22float2(h01);
        float2 f23 = __half22float2(h23);
        float e0 = EXP2F(f01.x + vv[j].x);
        float e1 = EXP2F(f01.y + vv[j].y);
        float e2 = EXP2F(f23.x + vv[j].z);
        float e3 = EXP2F(f23.y + vv[j].w);
        A += (e0 + e1) + (e2 + e3);
        if (FIN) B += e0 * f01.x + e1 * f01.y + e2 * f23.x + e3 * f23.y;
      }
    }
    #pragma unroll
    for (int s = 32; s; s >>= 1) {
      A += __shfl_xor(A, s);
      if (FIN) B += __shfl_xor(B, s);
    }
    if (lane == 0) {
      if (FIN) {
        atomicAdd(outp + pair, B * itau / ((float)MM * C2 * A));
      } else {
        upot[(size_t)pair * MM + m] = -L2M - LOG2F(A);
      }
    }
  }
}

// ---------------- v-pass: thread per 2 columns, u in LDS ---------------------
__global__ __launch_bounds__(128)
void v_kernel(const __half* __restrict__ cost, const float* __restrict__ upot,
              float* __restrict__ vpot)
{
  __shared__ float u_lds[MM];
  const int tid = threadIdx.x;
  const int pair   = blockIdx.x >> 2;
  const int kchunk = blockIdx.x & 3;

  const __half* cbase = cost + (size_t)pair * (MM * KMM);
  for (int i = tid; i < MM; i += 128) u_lds[i] = upot[(size_t)pair * MM + i];
  __syncthreads();

  const int kc = kchunk * 256 + 2 * tid;
  if (kc >= KMM) return;
  const __half* cp = cbase + kc;
  float Sa = 0.f, Sb = 0.f;
  #pragma unroll 4
  for (int m = 0; m < MM; ++m) {
    __half2 hv = *reinterpret_cast<const __half2*>(cp + (size_t)m * KMM);
    float2 f = __half22float2(hv);
    const float u = u_lds[m];
    Sa += EXP2F(f.x + u);
    Sb += EXP2F(f.y + u);
  }
  vpot[(size_t)pair * KMM + kc]     = -L2K - LOG2F(Sa);
  vpot[(size_t)pair * KMM + kc + 1] = -L2K - LOG2F(Sb);
}

extern "C" void kernel_launch(void* const* d_in, const int* in_sizes, int n_in,
                              void* d_out, int out_size, void* d_ws, size_t ws_size,
                              hipStream_t stream) {
  const float* qt  = (const float*)d_in[0];
  const float* st  = (const float*)d_in[1];
  const float* var = (const float*)d_in[2];
  const float* er  = (const float*)d_in[3];
  const float* tr  = (const float*)d_in[4];
  float* out = (float*)d_out;

  // ws layout (97,216,000 B total — proven-safe bound):
  //   cost fp16 : 250*196*980*2 = 96,040,000
  //   upot  f32 : 250*196*4    =    196,000
  //   vpot  f32 : 250*980*4    =    980,000   (doubles as colsum accumulator)
  char* ws = (char*)d_ws;
  __half* cost = (__half*)ws;
  float*  upot = (float*)(ws + 96040000);
  float*  vpot = (float*)(ws + 96040000 + 196000);

  hipMemsetAsync(out, 0, NPAIR * sizeof(float), stream);
  hipMemsetAsync(vpot, 0, (size_t)NPAIR * KMM * sizeof(float), stream);

  gemm_kernel<<<NPAIR * 16, 256, 0, stream>>>(qt, st, var, er, cost, vpot);
  vfin_kernel<<<(NPAIR * KMM + 255) / 256, 256, 0, stream>>>(vpot);

  for (int it = 0; it < NITER; ++it) {
    if (it > 0)
      v_kernel<<<NPAIR * 4, 128, 0, stream>>>(cost, upot, vpot);
    if (it < NITER - 1)
      u_kernel<false><<<NPAIR * 7, 256, 0, stream>>>(cost, vpot, upot, er, tr, out);
    else
      u_kernel<true ><<<NPAIR * 7, 256, 0, stream>>>(cost, vpot, upot, er, tr, out);
  }
}

// Round 5
// 500.145 us; speedup vs baseline: 1.7853x; 1.0719x over previous
//
#include <hip/hip_runtime.h>
#include <hip/hip_bf16.h>
#include <hip/hip_fp16.h>

#define QN    50
#define NWAY  5
#define NPAIR 250
#define MM    196
#define KMM   980
#define DD    640
#define NITER 5

#define L2M 7.6147098441152083f   // log2(196)
#define L2K 9.9366379390935392f   // log2(980)

typedef __attribute__((ext_vector_type(8)))  short short8;
typedef __attribute__((ext_vector_type(16))) float f32x16;

#define EXP2F(x) __builtin_exp2f(x)
#define LOG2F(x) __builtin_log2f(x)

__device__ __forceinline__ short bf16bits(float f) {
  __hip_bfloat16 h = __float2bfloat16(f);
  return *reinterpret_cast<short*>(&h);
}

// ---------------- tiled GEMM: cost[m][k] fp16 + fused colsum (v1 raw) --------
// 128x128 tile, BK=64, 4 waves as 2x2 of 64x64. LDS XOR-swizzle (slot^=row&7).
// XCD-aware bid swizzle (4000%8==0) + 2-phase register prefetch of next K-step.
__global__ __launch_bounds__(256, 3)
void gemm_kernel(const float* __restrict__ qt, const float* __restrict__ st,
                 const float* __restrict__ var, const float* __restrict__ epsr,
                 __half* __restrict__ cost, float* __restrict__ colsum)
{
  __shared__ __align__(16) unsigned short Ash[128 * 64];
  __shared__ __align__(16) unsigned short Bsh[128 * 64];
  __shared__ __align__(16) float w_lds[DD];
  __shared__ float cs_lds[128];
  __shared__ float red_s;

  const int tid  = threadIdx.x;
  const int wv   = tid >> 6;
  const int lane = tid & 63;
  const int l31  = lane & 31;
  const int lh   = lane >> 5;
  const int wm   = wv >> 1;        // wave m-half
  const int wn   = wv & 1;         // wave n-half

  // XCD swizzle: each XCD gets 500 consecutive logical tiles (~31 pairs)
  const int lg   = (blockIdx.x & 7) * 500 + (blockIdx.x >> 3);
  const int pair = lg >> 4;
  const int mt_  = (lg >> 3) & 1;  // m-tile 0/1
  const int nt_  = lg & 7;         // n-tile 0..7
  const int qi = pair / NWAY, wi = pair % NWAY;
  const int m0 = mt_ * 128, n0 = nt_ * 128;

  const float eps = logf(1.0f + expf(epsr[0])) + 1e-4f;
  const float C2  = 1.4426950408889634f / eps;

  // ---- per-dim weights into LDS ----
  float psum = 0.f;
  for (int d = tid; d < DD; d += 256) {
    float inv = 1.0f / (var[wi * DD + d] + 0.01f);
    w_lds[d] = inv; psum += inv;
  }
  #pragma unroll
  for (int s = 32; s; s >>= 1) psum += __shfl_xor(psum, s);
  if (tid == 0) red_s = 0.f;
  if (tid < 128) cs_lds[tid] = 0.f;
  __syncthreads();
  if (lane == 0) atomicAdd(&red_s, psum);
  __syncthreads();
  const float wsc = (float)DD / fmaxf(red_s, 1e-6f);
  for (int d = tid; d < DD; d += 256) w_lds[d] *= wsc;
  __syncthreads();

  const float* qb = qt + (size_t)qi * MM * DD;
  const float* sb = st + (size_t)wi * KMM * DD;

  f32x16 acc[2][2];
  #pragma unroll
  for (int i = 0; i < 2; ++i)
    #pragma unroll
    for (int j = 0; j < 2; ++j)
      #pragma unroll
      for (int e = 0; e < 16; ++e) acc[i][j][e] = 0.f;

  const int srow = tid >> 3;   // 0..31
  const int sslt = tid & 7;    // 16B slot 0..7 within a 128B row

  // prefetch registers: next K-step's A/B quarter-rows (16 float4)
  float4 ra0[4], ra1[4], rb0[4], rb1[4];

  #pragma unroll
  for (int i = 0; i < 4; ++i) {
    const int r = i * 32 + srow;
    const float* sa = qb + (size_t)min(m0 + r, MM - 1) * DD + sslt * 8;
    ra0[i] = *reinterpret_cast<const float4*>(sa);
    ra1[i] = *reinterpret_cast<const float4*>(sa + 4);
    const float* sbp = sb + (size_t)min(n0 + r, KMM - 1) * DD + sslt * 8;
    rb0[i] = *reinterpret_cast<const float4*>(sbp);
    rb1[i] = *reinterpret_cast<const float4*>(sbp + 4);
  }

  #pragma unroll
  for (int ks = 0; ks < 10; ++ks) {
    // ---- write staged regs to LDS (apply w to B here) ----
    const int kd = ks * 64 + sslt * 8;
    float4 w0 = *reinterpret_cast<const float4*>(w_lds + kd);
    float4 w1 = *reinterpret_cast<const float4*>(w_lds + kd + 4);
    #pragma unroll
    for (int i = 0; i < 4; ++i) {
      const int r = i * 32 + srow;
      const int wslt = (sslt ^ (r & 7)) * 8;
      short8 pk;
      pk[0] = bf16bits(ra0[i].x); pk[1] = bf16bits(ra0[i].y);
      pk[2] = bf16bits(ra0[i].z); pk[3] = bf16bits(ra0[i].w);
      pk[4] = bf16bits(ra1[i].x); pk[5] = bf16bits(ra1[i].y);
      pk[6] = bf16bits(ra1[i].z); pk[7] = bf16bits(ra1[i].w);
      *reinterpret_cast<short8*>(&Ash[r * 64 + wslt]) = pk;
      short8 qk;
      qk[0] = bf16bits(rb0[i].x * w0.x); qk[1] = bf16bits(rb0[i].y * w0.y);
      qk[2] = bf16bits(rb0[i].z * w0.z); qk[3] = bf16bits(rb0[i].w * w0.w);
      qk[4] = bf16bits(rb1[i].x * w1.x); qk[5] = bf16bits(rb1[i].y * w1.y);
      qk[6] = bf16bits(rb1[i].z * w1.z); qk[7] = bf16bits(rb1[i].w * w1.w);
      *reinterpret_cast<short8*>(&Bsh[r * 64 + wslt]) = qk;
    }
    __syncthreads();
    // ---- issue next K-step's global loads (overlap with MFMA below) ----
    if (ks < 9) {
      const int kn = (ks + 1) * 64 + sslt * 8;
      #pragma unroll
      for (int i = 0; i < 4; ++i) {
        const int r = i * 32 + srow;
        const float* sa = qb + (size_t)min(m0 + r, MM - 1) * DD + kn;
        ra0[i] = *reinterpret_cast<const float4*>(sa);
        ra1[i] = *reinterpret_cast<const float4*>(sa + 4);
        const float* sbp = sb + (size_t)min(n0 + r, KMM - 1) * DD + kn;
        rb0[i] = *reinterpret_cast<const float4*>(sbp);
        rb1[i] = *reinterpret_cast<const float4*>(sbp + 4);
      }
    }
    // ---- compute: 4 k-steps of 16, 2x2 MFMA 32x32x16 ----
    #pragma unroll
    for (int kk = 0; kk < 4; ++kk) {
      const int ph = ((kk * 2 + lh) ^ (l31 & 7)) * 8;
      short8 a0 = *reinterpret_cast<short8*>(&Ash[(wm * 64      + l31) * 64 + ph]);
      short8 a1 = *reinterpret_cast<short8*>(&Ash[(wm * 64 + 32 + l31) * 64 + ph]);
      short8 b0 = *reinterpret_cast<short8*>(&Bsh[(wn * 64      + l31) * 64 + ph]);
      short8 b1 = *reinterpret_cast<short8*>(&Bsh[(wn * 64 + 32 + l31) * 64 + ph]);
      acc[0][0] = __builtin_amdgcn_mfma_f32_32x32x16_bf16(a0, b0, acc[0][0], 0, 0, 0);
      acc[0][1] = __builtin_amdgcn_mfma_f32_32x32x16_bf16(a0, b1, acc[0][1], 0, 0, 0);
      acc[1][0] = __builtin_amdgcn_mfma_f32_32x32x16_bf16(a1, b0, acc[1][0], 0, 0, 0);
      acc[1][1] = __builtin_amdgcn_mfma_f32_32x32x16_bf16(a1, b1, acc[1][1], 0, 0, 0);
    }
    __syncthreads();
  }

  // ---- epilogue: fp16 store + per-column exp2 partial sums (u0 = 0) ----
  __half* cb = cost + (size_t)pair * MM * KMM;
  #pragma unroll
  for (int nt = 0; nt < 2; ++nt) {
    const int ncol = n0 + wn * 64 + nt * 32 + l31;
    float part = 0.f;
    #pragma unroll
    for (int mt = 0; mt < 2; ++mt) {
      #pragma unroll
      for (int r = 0; r < 16; ++r) {
        const int mrow = m0 + wm * 64 + mt * 32 + (r & 3) + 8 * (r >> 2) + 4 * lh;
        if (mrow < MM && ncol < KMM) {
          const float val = (acc[mt][nt][r] - 1.0f) * C2;
          cb[(size_t)mrow * KMM + ncol] = __float2half(val);
          part += EXP2F(val);
        }
      }
    }
    atomicAdd(&cs_lds[wn * 64 + nt * 32 + l31], part);
  }
  __syncthreads();
  if (tid < 128 && n0 + tid < KMM)
    atomicAdd(&colsum[(size_t)pair * KMM + n0 + tid], cs_lds[tid]);
}

// ---------------- finish v1: vpot = -L2K - log2(colsum), in place ------------
__global__ __launch_bounds__(256)
void vfin_kernel(float* __restrict__ vpot)
{
  const int i = blockIdx.x * 256 + threadIdx.x;
  if (i < NPAIR * KMM) vpot[i] = -L2K - LOG2F(vpot[i]);
}

// ---------------- u-pass: wave per row, v in registers; FIN fuses OT ---------
template<bool FIN>
__global__ __launch_bounds__(256)
void u_kernel(const __half* __restrict__ cost, const float* __restrict__ vpot,
              float* __restrict__ upot, const float* __restrict__ epsr,
              const float* __restrict__ taur, float* __restrict__ outp)
{
  const int tid  = threadIdx.x;
  const int wave = tid >> 6;
  const int lane = tid & 63;
  const int pair   = blockIdx.x / 7;
  const int mchunk = blockIdx.x % 7;

  const __half* cbase = cost + (size_t)pair * (MM * KMM);
  const float*  vp    = vpot + (size_t)pair * KMM;

  float4 vv[4];
  #pragma unroll
  for (int j = 0; j < 4; ++j) {
    const int k = 4 * lane + 256 * j;
    vv[j] = (k < KMM) ? *reinterpret_cast<const float4*>(vp + k)
                      : make_float4(0.f, 0.f, 0.f, 0.f);
  }

  float C2 = 0.f, itau = 0.f;
  if (FIN) {
    const float eps = logf(1.0f + expf(epsr[0])) + 1e-4f;
    C2 = 1.4426950408889634f / eps;
    itau = 1.0f / (logf(1.0f + expf(taur[0])) + 0.01f);
  }

  #pragma unroll
  for (int r = 0; r < 7; ++r) {
    const int m = mchunk * 28 + wave * 7 + r;
    const __half* rp = cbase + (size_t)m * KMM;
    float A = 0.f, B = 0.f;
    #pragma unroll
    for (int j = 0; j < 4; ++j) {
      const int k = 4 * lane + 256 * j;
      if (k < KMM) {
        uint2 raw = *reinterpret_cast<const uint2*>(rp + k);
        __half2 h01 = *reinterpret_cast<const __half2*>(&raw.x);
        __half2 h23 = *reinterpret_cast<const __half2*>(&raw.y);
        float2 f01 = __half22float2(h01);
        float2 f23 = __half22float2(h23);
        float e0 = EXP2F(f01.x + vv[j].x);
        float e1 = EXP2F(f01.y + vv[j].y);
        float e2 = EXP2F(f23.x + vv[j].z);
        float e3 = EXP2F(f23.y + vv[j].w);
        A += (e0 + e1) + (e2 + e3);
        if (FIN) B += e0 * f01.x + e1 * f01.y + e2 * f23.x + e3 * f23.y;
      }
    }
    #pragma unroll
    for (int s = 32; s; s >>= 1) {
      A += __shfl_xor(A, s);
      if (FIN) B += __shfl_xor(B, s);
    }
    if (lane == 0) {
      if (FIN) {
        atomicAdd(outp + pair, B * itau / ((float)MM * C2 * A));
      } else {
        upot[(size_t)pair * MM + m] = -L2M - LOG2F(A);
      }
    }
  }
}

// ---------------- v-pass: block per pair, 8 waves read rows coalesced --------
// Wave w handles rows m = w, w+8, ...; lane keeps 16 column-partials in regs;
// cross-wave fold via LDS part[8][1024].
__global__ __launch_bounds__(512)
void v_kernel(const __half* __restrict__ cost, const float* __restrict__ upot,
              float* __restrict__ vpot)
{
  __shared__ float u_lds[MM];
  __shared__ float part[8][1024];
  const int tid  = threadIdx.x;
  const int wave = tid >> 6;
  const int lane = tid & 63;
  const int pair = blockIdx.x;

  if (tid < MM) u_lds[tid] = upot[(size_t)pair * MM + tid];
  __syncthreads();

  const int c1 = 8 * lane;         // cols c1..c1+7   (max 511, always valid)
  const int c2 = 512 + 8 * lane;   // cols c2..c2+7   (mask >= 980)

  float acc[16];
  #pragma unroll
  for (int e = 0; e < 16; ++e) acc[e] = 0.f;

  const __half* cb = cost + (size_t)pair * MM * KMM;
  #pragma unroll 4
  for (int m = wave; m < MM; m += 8) {
    const __half* rp = cb + (size_t)m * KMM;
    const float u = u_lds[m];
    // 8B loads (row base is 8B-aligned: 1960 % 8 == 0)
    uint2 ra = *reinterpret_cast<const uint2*>(rp + c1);
    uint2 rb = *reinterpret_cast<const uint2*>(rp + c1 + 4);
    uint2 rc = *reinterpret_cast<const uint2*>(rp + c2);
    uint2 rd = *reinterpret_cast<const uint2*>(rp + c2 + 4);
    float2 f0 = __half22float2(*reinterpret_cast<const __half2*>(&ra.x));
    float2 f1 = __half22float2(*reinterpret_cast<const __half2*>(&ra.y));
    float2 f2 = __half22float2(*reinterpret_cast<const __half2*>(&rb.x));
    float2 f3 = __half22float2(*reinterpret_cast<const __half2*>(&rb.y));
    acc[0] += EXP2F(f0.x + u); acc[1] += EXP2F(f0.y + u);
    acc[2] += EXP2F(f1.x + u); acc[3] += EXP2F(f1.y + u);
    acc[4] += EXP2F(f2.x + u); acc[5] += EXP2F(f2.y + u);
    acc[6] += EXP2F(f3.x + u); acc[7] += EXP2F(f3.y + u);
    float2 g0 = __half22float2(*reinterpret_cast<const __half2*>(&rc.x));
    float2 g1 = __half22float2(*reinterpret_cast<const __half2*>(&rc.y));
    float2 g2 = __half22float2(*reinterpret_cast<const __half2*>(&rd.x));
    float2 g3 = __half22float2(*reinterpret_cast<const __half2*>(&rd.y));
    // mask tail cols >= 980 AFTER exp2 (Inf/NaN from slop bytes discarded)
    float e8  = EXP2F(g0.x + u), e9  = EXP2F(g0.y + u);
    float e10 = EXP2F(g1.x + u), e11 = EXP2F(g1.y + u);
    float e12 = EXP2F(g2.x + u), e13 = EXP2F(g2.y + u);
    float e14 = EXP2F(g3.x + u), e15 = EXP2F(g3.y + u);
    acc[8]  += (c2 + 0 < KMM) ? e8  : 0.f;
    acc[9]  += (c2 + 1 < KMM) ? e9  : 0.f;
    acc[10] += (c2 + 2 < KMM) ? e10 : 0.f;
    acc[11] += (c2 + 3 < KMM) ? e11 : 0.f;
    acc[12] += (c2 + 4 < KMM) ? e12 : 0.f;
    acc[13] += (c2 + 5 < KMM) ? e13 : 0.f;
    acc[14] += (c2 + 6 < KMM) ? e14 : 0.f;
    acc[15] += (c2 + 7 < KMM) ? e15 : 0.f;
  }

  #pragma unroll
  for (int e = 0; e < 8; ++e) part[wave][c1 + e] = acc[e];
  #pragma unroll
  for (int e = 0; e < 8; ++e) part[wave][c2 + e] = acc[8 + e];
  __syncthreads();

  for (int k = tid; k < KMM; k += 512) {
    float s = 0.f;
    #pragma unroll
    for (int w = 0; w < 8; ++w) s += part[w][k];
    vpot[(size_t)pair * KMM + k] = -L2K - LOG2F(s);
  }
}

extern "C" void kernel_launch(void* const* d_in, const int* in_sizes, int n_in,
                              void* d_out, int out_size, void* d_ws, size_t ws_size,
                              hipStream_t stream) {
  const float* qt  = (const float*)d_in[0];
  const float* st  = (const float*)d_in[1];
  const float* var = (const float*)d_in[2];
  const float* er  = (const float*)d_in[3];
  const float* tr  = (const float*)d_in[4];
  float* out = (float*)d_out;

  // ws layout (97,216,000 B total — proven-safe bound):
  //   cost fp16 : 250*196*980*2 = 96,040,000
  //   upot  f32 : 250*196*4    =    196,000
  //   vpot  f32 : 250*980*4    =    980,000   (doubles as colsum accumulator)
  char* ws = (char*)d_ws;
  __half* cost = (__half*)ws;
  float*  upot = (float*)(ws + 96040000);
  float*  vpot = (float*)(ws + 96040000 + 196000);

  hipMemsetAsync(out, 0, NPAIR * sizeof(float), stream);
  hipMemsetAsync(vpot, 0, (size_t)NPAIR * KMM * sizeof(float), stream);

  gemm_kernel<<<NPAIR * 16, 256, 0, stream>>>(qt, st, var, er, cost, vpot);
  vfin_kernel<<<(NPAIR * KMM + 255) / 256, 256, 0, stream>>>(vpot);

  for (int it = 0; it < NITER; ++it) {
    if (it > 0)
      v_kernel<<<NPAIR, 512, 0, stream>>>(cost, upot, vpot);
    if (it < NITER - 1)
      u_kernel<false><<<NPAIR * 7, 256, 0, stream>>>(cost, vpot, upot, er, tr, out);
    else
      u_kernel<true ><<<NPAIR * 7, 256, 0, stream>>>(cost, vpot, upot, er, tr, out);
  }
}

// Round 8
// 439.766 us; speedup vs baseline: 2.0304x; 1.1373x over previous
//
#include <hip/hip_runtime.h>
#include <hip/hip_bf16.h>
#include <hip/hip_fp16.h>

#define QN    50
#define NWAY  5
#define NPAIR 250
#define MM    196
#define KMM   980
#define DD    640
#define NITER 5

typedef __attribute__((ext_vector_type(8)))  short short8;
typedef __attribute__((ext_vector_type(16))) float f32x16;

#define EXP2F(x) __builtin_exp2f(x)
#define LOG2F(x) __builtin_log2f(x)
#define RCPF(x)  __builtin_amdgcn_rcpf(x)

__device__ __forceinline__ short bf16bits(float f) {
  __hip_bfloat16 h = __float2bfloat16(f);
  return *reinterpret_cast<short*>(&h);
}

// packed-half2 atomic add via CAS (no atomicAdd(__half2*) overload in ROCm7)
__device__ __forceinline__ void h2AtomicAdd(__half2* addr, float a, float b) {
  unsigned int* ui = reinterpret_cast<unsigned int*>(addr);
  unsigned int old = __hip_atomic_load(ui, __ATOMIC_RELAXED, __HIP_MEMORY_SCOPE_AGENT);
  unsigned int assumed;
  do {
    assumed = old;
    __half2 cur = *reinterpret_cast<__half2*>(&assumed);
    float2 cf = __half22float2(cur);
    __half2 sum = __floats2half2_rn(cf.x + a, cf.y + b);
    unsigned int ns = *reinterpret_cast<unsigned int*>(&sum);
    old = atomicCAS(ui, assumed, ns);
  } while (old != assumed);
}

// ---------------- tiled GEMM: cost[m][k] fp16 + fused raw colsum T1 ----------
// 128x128 tile, BK=64, 4 waves as 2x2 of 64x64. LDS XOR-swizzle (slot^=row&7).
// XCD-aware bid swizzle (4000%8==0) + 2-phase register prefetch of next K-step.
// Epilogue: T1[k] += sum_m 2^c (u0=0) via CAS half2 atomics.
__global__ __launch_bounds__(256, 3)
void gemm_kernel(const float* __restrict__ qt, const float* __restrict__ st,
                 const float* __restrict__ var, const float* __restrict__ epsr,
                 __half* __restrict__ cost, __half* __restrict__ T1)
{
  __shared__ __align__(16) unsigned short Ash[128 * 64];
  __shared__ __align__(16) unsigned short Bsh[128 * 64];
  __shared__ __align__(16) float w_lds[DD];
  __shared__ float cs_lds[128];
  __shared__ float red_s;

  const int tid  = threadIdx.x;
  const int wv   = tid >> 6;
  const int lane = tid & 63;
  const int l31  = lane & 31;
  const int lh   = lane >> 5;
  const int wm   = wv >> 1;        // wave m-half
  const int wn   = wv & 1;         // wave n-half

  // XCD swizzle: each XCD gets 500 consecutive logical tiles (~31 pairs)
  const int lg   = (blockIdx.x & 7) * 500 + (blockIdx.x >> 3);
  const int pair = lg >> 4;
  const int mt_  = (lg >> 3) & 1;  // m-tile 0/1
  const int nt_  = lg & 7;         // n-tile 0..7
  const int qi = pair / NWAY, wi = pair % NWAY;
  const int m0 = mt_ * 128, n0 = nt_ * 128;

  const float eps = logf(1.0f + expf(epsr[0])) + 1e-4f;
  const float C2  = 1.4426950408889634f / eps;

  // ---- per-dim weights into LDS ----
  float psum = 0.f;
  for (int d = tid; d < DD; d += 256) {
    float inv = 1.0f / (var[wi * DD + d] + 0.01f);
    w_lds[d] = inv; psum += inv;
  }
  #pragma unroll
  for (int s = 32; s; s >>= 1) psum += __shfl_xor(psum, s);
  if (tid == 0) red_s = 0.f;
  if (tid < 128) cs_lds[tid] = 0.f;
  __syncthreads();
  if (lane == 0) atomicAdd(&red_s, psum);
  __syncthreads();
  const float wsc = (float)DD / fmaxf(red_s, 1e-6f);
  for (int d = tid; d < DD; d += 256) w_lds[d] *= wsc;
  __syncthreads();

  const float* qb = qt + (size_t)qi * MM * DD;
  const float* sb = st + (size_t)wi * KMM * DD;

  f32x16 acc[2][2];
  #pragma unroll
  for (int i = 0; i < 2; ++i)
    #pragma unroll
    for (int j = 0; j < 2; ++j)
      #pragma unroll
      for (int e = 0; e < 16; ++e) acc[i][j][e] = 0.f;

  const int srow = tid >> 3;   // 0..31
  const int sslt = tid & 7;    // 16B slot 0..7 within a 128B row

  // prefetch registers: next K-step's A/B quarter-rows (16 float4)
  float4 ra0[4], ra1[4], rb0[4], rb1[4];

  #pragma unroll
  for (int i = 0; i < 4; ++i) {
    const int r = i * 32 + srow;
    const float* sa = qb + (size_t)min(m0 + r, MM - 1) * DD + sslt * 8;
    ra0[i] = *reinterpret_cast<const float4*>(sa);
    ra1[i] = *reinterpret_cast<const float4*>(sa + 4);
    const float* sbp = sb + (size_t)min(n0 + r, KMM - 1) * DD + sslt * 8;
    rb0[i] = *reinterpret_cast<const float4*>(sbp);
    rb1[i] = *reinterpret_cast<const float4*>(sbp + 4);
  }

  #pragma unroll
  for (int ks = 0; ks < 10; ++ks) {
    // ---- write staged regs to LDS (apply w to B here) ----
    const int kd = ks * 64 + sslt * 8;
    float4 w0 = *reinterpret_cast<const float4*>(w_lds + kd);
    float4 w1 = *reinterpret_cast<const float4*>(w_lds + kd + 4);
    #pragma unroll
    for (int i = 0; i < 4; ++i) {
      const int r = i * 32 + srow;
      const int wslt = (sslt ^ (r & 7)) * 8;
      short8 pk;
      pk[0] = bf16bits(ra0[i].x); pk[1] = bf16bits(ra0[i].y);
      pk[2] = bf16bits(ra0[i].z); pk[3] = bf16bits(ra0[i].w);
      pk[4] = bf16bits(ra1[i].x); pk[5] = bf16bits(ra1[i].y);
      pk[6] = bf16bits(ra1[i].z); pk[7] = bf16bits(ra1[i].w);
      *reinterpret_cast<short8*>(&Ash[r * 64 + wslt]) = pk;
      short8 qk;
      qk[0] = bf16bits(rb0[i].x * w0.x); qk[1] = bf16bits(rb0[i].y * w0.y);
      qk[2] = bf16bits(rb0[i].z * w0.z); qk[3] = bf16bits(rb0[i].w * w0.w);
      qk[4] = bf16bits(rb1[i].x * w1.x); qk[5] = bf16bits(rb1[i].y * w1.y);
      qk[6] = bf16bits(rb1[i].z * w1.z); qk[7] = bf16bits(rb1[i].w * w1.w);
      *reinterpret_cast<short8*>(&Bsh[r * 64 + wslt]) = qk;
    }
    __syncthreads();
    // ---- issue next K-step's global loads (overlap with MFMA below) ----
    if (ks < 9) {
      const int kn = (ks + 1) * 64 + sslt * 8;
      #pragma unroll
      for (int i = 0; i < 4; ++i) {
        const int r = i * 32 + srow;
        const float* sa = qb + (size_t)min(m0 + r, MM - 1) * DD + kn;
        ra0[i] = *reinterpret_cast<const float4*>(sa);
        ra1[i] = *reinterpret_cast<const float4*>(sa + 4);
        const float* sbp = sb + (size_t)min(n0 + r, KMM - 1) * DD + kn;
        rb0[i] = *reinterpret_cast<const float4*>(sbp);
        rb1[i] = *reinterpret_cast<const float4*>(sbp + 4);
      }
    }
    // ---- compute: 4 k-steps of 16, 2x2 MFMA 32x32x16 ----
    #pragma unroll
    for (int kk = 0; kk < 4; ++kk) {
      const int ph = ((kk * 2 + lh) ^ (l31 & 7)) * 8;
      short8 a0 = *reinterpret_cast<short8*>(&Ash[(wm * 64      + l31) * 64 + ph]);
      short8 a1 = *reinterpret_cast<short8*>(&Ash[(wm * 64 + 32 + l31) * 64 + ph]);
      short8 b0 = *reinterpret_cast<short8*>(&Bsh[(wn * 64      + l31) * 64 + ph]);
      short8 b1 = *reinterpret_cast<short8*>(&Bsh[(wn * 64 + 32 + l31) * 64 + ph]);
      acc[0][0] = __builtin_amdgcn_mfma_f32_32x32x16_bf16(a0, b0, acc[0][0], 0, 0, 0);
      acc[0][1] = __builtin_amdgcn_mfma_f32_32x32x16_bf16(a0, b1, acc[0][1], 0, 0, 0);
      acc[1][0] = __builtin_amdgcn_mfma_f32_32x32x16_bf16(a1, b0, acc[1][0], 0, 0, 0);
      acc[1][1] = __builtin_amdgcn_mfma_f32_32x32x16_bf16(a1, b1, acc[1][1], 0, 0, 0);
    }
    __syncthreads();
  }

  // ---- epilogue: fp16 store + per-column exp2 partial sums (u0 = 0) ----
  __half* cb = cost + (size_t)pair * MM * KMM;
  #pragma unroll
  for (int nt = 0; nt < 2; ++nt) {
    const int ncol = n0 + wn * 64 + nt * 32 + l31;
    float part = 0.f;
    #pragma unroll
    for (int mt = 0; mt < 2; ++mt) {
      #pragma unroll
      for (int r = 0; r < 16; ++r) {
        const int mrow = m0 + wm * 64 + mt * 32 + (r & 3) + 8 * (r >> 2) + 4 * lh;
        if (mrow < MM && ncol < KMM) {
          const float val = (acc[mt][nt][r] - 1.0f) * C2;
          cb[(size_t)mrow * KMM + ncol] = __float2half(val);
          part += EXP2F(val);
        }
      }
    }
    atomicAdd(&cs_lds[wn * 64 + nt * 32 + l31], part);
  }
  __syncthreads();
  // colsum: 2 CAS-half2 atomics per column pair per block (one per m-tile)
  if (tid < 64) {
    const int c0 = n0 + 2 * tid;               // even; c0+1 <= 979 when c0 < 980
    if (c0 < KMM)
      h2AtomicAdd(reinterpret_cast<__half2*>(T1 + (size_t)pair * KMM + c0),
                  cs_lds[2 * tid], cs_lds[2 * tid + 1]);
  }
}

// ---------------- fused sweep: one matrix pass per Sinkhorn iteration --------
// Per row m (wave-owned): A = sum_k p_k * iT_k  (p = 2^c, iT = 1/(980*T[k]) = V)
//   -> 2^{u_new} = 1/(196*A); column partials T'[k] += p_k * 2^{u_new}.
// Non-FIN: fold 4 waves in LDS, CAS-half2 atomics into Tout (zeroed).
// FIN: OT contraction only: out[pair] += (sum e*c) * 2^u / (C2*tau).
template<bool FIN>
__global__ __launch_bounds__(256)
void sweep_kernel(const __half* __restrict__ cost, const __half* __restrict__ Tin,
                  __half* __restrict__ Tout, const float* __restrict__ epsr,
                  const float* __restrict__ taur, float* __restrict__ outp)
{
  __shared__ float part[4][1024];
  const int tid  = threadIdx.x;
  const int wave = tid >> 6;
  const int lane = tid & 63;
  const int pair   = blockIdx.x / 7;
  const int mchunk = blockIdx.x % 7;

  const __half* cb = cost + (size_t)pair * MM * KMM;
  const __half* tp = Tin  + (size_t)pair * KMM;

  float iT[16], acc[16], p[16];
  #pragma unroll
  for (int j = 0; j < 4; ++j) {
    const int k = 4 * lane + 256 * j;
    if (k < KMM) {
      uint2 raw = *reinterpret_cast<const uint2*>(tp + k);
      float2 t01 = __half22float2(*reinterpret_cast<const __half2*>(&raw.x));
      float2 t23 = __half22float2(*reinterpret_cast<const __half2*>(&raw.y));
      iT[4 * j + 0] = RCPF(980.0f * t01.x);
      iT[4 * j + 1] = RCPF(980.0f * t01.y);
      iT[4 * j + 2] = RCPF(980.0f * t23.x);
      iT[4 * j + 3] = RCPF(980.0f * t23.y);
    } else {
      iT[4 * j + 0] = 0.f; iT[4 * j + 1] = 0.f;
      iT[4 * j + 2] = 0.f; iT[4 * j + 3] = 0.f;
    }
  }
  #pragma unroll
  for (int e = 0; e < 16; ++e) acc[e] = 0.f;

  float scal = 0.f, rowacc = 0.f;
  if (FIN) {
    const float eps = logf(1.0f + expf(epsr[0])) + 1e-4f;
    const float C2  = 1.4426950408889634f / eps;
    const float tau = logf(1.0f + expf(taur[0])) + 0.01f;
    scal = 1.0f / (tau * C2);
  }

  #pragma unroll
  for (int r = 0; r < 7; ++r) {
    const int m = mchunk * 28 + wave * 7 + r;
    const __half* rp = cb + (size_t)m * KMM;
    float A = 0.f, Bv = 0.f;
    #pragma unroll
    for (int j = 0; j < 4; ++j) {
      const int k = 4 * lane + 256 * j;
      if (k < KMM) {
        uint2 raw = *reinterpret_cast<const uint2*>(rp + k);
        float2 c01 = __half22float2(*reinterpret_cast<const __half2*>(&raw.x));
        float2 c23 = __half22float2(*reinterpret_cast<const __half2*>(&raw.y));
        float p0 = EXP2F(c01.x), p1 = EXP2F(c01.y);
        float p2 = EXP2F(c23.x), p3 = EXP2F(c23.y);
        p[4 * j + 0] = p0; p[4 * j + 1] = p1;
        p[4 * j + 2] = p2; p[4 * j + 3] = p3;
        float e0 = p0 * iT[4 * j + 0], e1 = p1 * iT[4 * j + 1];
        float e2 = p2 * iT[4 * j + 2], e3 = p3 * iT[4 * j + 3];
        A += (e0 + e1) + (e2 + e3);
        if (FIN) Bv += e0 * c01.x + e1 * c01.y + e2 * c23.x + e3 * c23.y;
      } else {
        p[4 * j + 0] = 0.f; p[4 * j + 1] = 0.f;
        p[4 * j + 2] = 0.f; p[4 * j + 3] = 0.f;
      }
    }
    #pragma unroll
    for (int s = 32; s; s >>= 1) {
      A += __shfl_xor(A, s);
      if (FIN) Bv += __shfl_xor(Bv, s);
    }
    const float up = RCPF(196.0f * A);      // = 2^{u_new}
    if (FIN) {
      rowacc += Bv * up;
    } else {
      #pragma unroll
      for (int e = 0; e < 16; ++e) acc[e] += p[e] * up;
    }
  }

  if (FIN) {
    if (lane == 0) atomicAdd(outp + pair, rowacc * scal);
  } else {
    #pragma unroll
    for (int j = 0; j < 4; ++j) {
      const int k = 4 * lane + 256 * j;
      part[wave][k + 0] = acc[4 * j + 0];
      part[wave][k + 1] = acc[4 * j + 1];
      part[wave][k + 2] = acc[4 * j + 2];
      part[wave][k + 3] = acc[4 * j + 3];
    }
    __syncthreads();
    __half* top = Tout + (size_t)pair * KMM;
    for (int c2 = tid; c2 < KMM / 2; c2 += 256) {
      const int c = 2 * c2;
      float s0 = part[0][c]     + part[1][c]     + part[2][c]     + part[3][c];
      float s1 = part[0][c + 1] + part[1][c + 1] + part[2][c + 1] + part[3][c + 1];
      h2AtomicAdd(reinterpret_cast<__half2*>(top + c), s0, s1);
    }
  }
}

extern "C" void kernel_launch(void* const* d_in, const int* in_sizes, int n_in,
                              void* d_out, int out_size, void* d_ws, size_t ws_size,
                              hipStream_t stream) {
  const float* qt  = (const float*)d_in[0];
  const float* st  = (const float*)d_in[1];
  const float* var = (const float*)d_in[2];
  const float* er  = (const float*)d_in[3];
  const float* tr  = (const float*)d_in[4];
  float* out = (float*)d_out;

  // ws layout (97,020,000 B <= proven 97,216,000 budget):
  //   cost fp16 : 250*196*980*2 = 96,040,000
  //   Ta   fp16 : 250*980*2     =    490,000   (raw colsum ping)
  //   Tb   fp16 : 250*980*2     =    490,000   (raw colsum pong)
  char* ws = (char*)d_ws;
  __half* cost = (__half*)ws;
  __half* Ta   = (__half*)(ws + 96040000);
  __half* Tb   = (__half*)(ws + 96040000 + 490000);

  (void)hipMemsetAsync(out, 0, NPAIR * sizeof(float), stream);
  (void)hipMemsetAsync(Ta, 0, (size_t)NPAIR * KMM * sizeof(__half), stream);

  gemm_kernel<<<NPAIR * 16, 256, 0, stream>>>(qt, st, var, er, cost, Ta);

  __half* cur = Ta;
  __half* nxt = Tb;
  for (int it = 0; it < NITER - 1; ++it) {
    (void)hipMemsetAsync(nxt, 0, (size_t)NPAIR * KMM * sizeof(__half), stream);
    sweep_kernel<false><<<NPAIR * 7, 256, 0, stream>>>(cost, cur, nxt, er, tr, out);
    __half* t = cur; cur = nxt; nxt = t;
  }
  sweep_kernel<true><<<NPAIR * 7, 256, 0, stream>>>(cost, cur, nullptr, er, tr, out);
}

// Round 9
// 392.067 us; speedup vs baseline: 2.2774x; 1.1217x over previous
//
#include <hip/hip_runtime.h>
#include <hip/hip_bf16.h>
#include <hip/hip_fp16.h>

#define QN    50
#define NWAY  5
#define NPAIR 250
#define MM    196
#define KMM   980
#define KP    984     // fp8 row stride (8B aligned)
#define DD    640
#define NITER 5

typedef __attribute__((ext_vector_type(8)))  short short8;
typedef __attribute__((ext_vector_type(16))) float f32x16;

#define EXP2F(x) __builtin_exp2f(x)
#define RCPF(x)  __builtin_amdgcn_rcpf(x)

#define E4M3_UP 1.3292279957849159e36f   // 2^120
#define E4M3_DN 7.5231638452626401e-37f  // 2^-120

__device__ __forceinline__ short bf16bits(float f) {
  __hip_bfloat16 h = __float2bfloat16(f);
  return *reinterpret_cast<short*>(&h);
}

// e4m3fn encode: clamp to 448, scale into f32 bit-domain, round mantissa
__device__ __forceinline__ unsigned int f32_to_e4m3(float x) {
  unsigned int b = __float_as_uint(x);
  unsigned int sgn = (b >> 24) & 0x80u;
  float a = __uint_as_float(b & 0x7FFFFFFFu);
  a = fminf(a, 448.0f);
  unsigned int z = __float_as_uint(a * E4M3_DN);
  unsigned int mag = (z + 0x00080000u) >> 20;   // round-half-up; max 0x7E (no NaN)
  return sgn | mag;
}
__device__ __forceinline__ float e4m3_to_f32(unsigned int v) {
  return __uint_as_float(((v & 0x80u) << 24) | ((v & 0x7Fu) << 20)) * E4M3_UP;
}
__device__ __forceinline__ float dec8(unsigned int word, int byte) {
  return e4m3_to_f32((word >> (8 * byte)) & 0xFFu);
}

// packed-half2 atomic add via CAS (no atomicAdd(__half2*) overload in ROCm7)
__device__ __forceinline__ void h2AtomicAdd(__half2* addr, float a, float b) {
  unsigned int* ui = reinterpret_cast<unsigned int*>(addr);
  unsigned int old = __hip_atomic_load(ui, __ATOMIC_RELAXED, __HIP_MEMORY_SCOPE_AGENT);
  unsigned int assumed;
  do {
    assumed = old;
    __half2 cur = *reinterpret_cast<__half2*>(&assumed);
    float2 cf = __half22float2(cur);
    __half2 sum = __floats2half2_rn(cf.x + a, cf.y + b);
    unsigned int ns = *reinterpret_cast<unsigned int*>(&sum);
    old = atomicCAS(ui, assumed, ns);
  } while (old != assumed);
}

// ---------------- tiled GEMM: cost[m][k] = e4m3(sim*C2) + fused colsum T1 ----
// 128x128 tile, BK=64, 4 waves 2x2 of 64x64, LDS XOR-swizzle, 2-phase prefetch.
// Way-major pair order (pair = wi*50+qi) so each XCD keeps ONE way's s-slice
// (2.5 MB) L2-resident. T1[k] += sum_m 2^r (u0=0) via CAS half2 atomics.
__global__ __launch_bounds__(256, 3)
void gemm_kernel(const float* __restrict__ qt, const float* __restrict__ st,
                 const float* __restrict__ var, const float* __restrict__ epsr,
                 unsigned char* __restrict__ cost, __half* __restrict__ T1)
{
  __shared__ __align__(16) unsigned short Ash[128 * 64];
  __shared__ __align__(16) unsigned short Bsh[128 * 64];
  __shared__ __align__(16) float w_lds[DD];
  __shared__ float cs_lds[128];
  __shared__ float red_s;

  const int tid  = threadIdx.x;
  const int wv   = tid >> 6;
  const int lane = tid & 63;
  const int l31  = lane & 31;
  const int lh   = lane >> 5;
  const int wm   = wv >> 1;
  const int wn   = wv & 1;

  const int lg   = (blockIdx.x & 7) * 500 + (blockIdx.x >> 3);
  const int pair = lg >> 4;
  const int mt_  = (lg >> 3) & 1;
  const int nt_  = lg & 7;
  const int wi = pair / 50, qi = pair % 50;     // way-major
  const int m0 = mt_ * 128, n0 = nt_ * 128;

  const float eps = logf(1.0f + expf(epsr[0])) + 1e-4f;
  const float C2  = 1.4426950408889634f / eps;

  float psum = 0.f;
  for (int d = tid; d < DD; d += 256) {
    float inv = 1.0f / (var[wi * DD + d] + 0.01f);
    w_lds[d] = inv; psum += inv;
  }
  #pragma unroll
  for (int s = 32; s; s >>= 1) psum += __shfl_xor(psum, s);
  if (tid == 0) red_s = 0.f;
  if (tid < 128) cs_lds[tid] = 0.f;
  __syncthreads();
  if (lane == 0) atomicAdd(&red_s, psum);
  __syncthreads();
  const float wsc = (float)DD / fmaxf(red_s, 1e-6f);
  for (int d = tid; d < DD; d += 256) w_lds[d] *= wsc;
  __syncthreads();

  const float* qb = qt + (size_t)qi * MM * DD;
  const float* sb = st + (size_t)wi * KMM * DD;

  f32x16 acc[2][2];
  #pragma unroll
  for (int i = 0; i < 2; ++i)
    #pragma unroll
    for (int j = 0; j < 2; ++j)
      #pragma unroll
      for (int e = 0; e < 16; ++e) acc[i][j][e] = 0.f;

  const int srow = tid >> 3;
  const int sslt = tid & 7;

  float4 ra0[4], ra1[4], rb0[4], rb1[4];
  #pragma unroll
  for (int i = 0; i < 4; ++i) {
    const int r = i * 32 + srow;
    const float* sa = qb + (size_t)min(m0 + r, MM - 1) * DD + sslt * 8;
    ra0[i] = *reinterpret_cast<const float4*>(sa);
    ra1[i] = *reinterpret_cast<const float4*>(sa + 4);
    const float* sbp = sb + (size_t)min(n0 + r, KMM - 1) * DD + sslt * 8;
    rb0[i] = *reinterpret_cast<const float4*>(sbp);
    rb1[i] = *reinterpret_cast<const float4*>(sbp + 4);
  }

  #pragma unroll
  for (int ks = 0; ks < 10; ++ks) {
    const int kd = ks * 64 + sslt * 8;
    float4 w0 = *reinterpret_cast<const float4*>(w_lds + kd);
    float4 w1 = *reinterpret_cast<const float4*>(w_lds + kd + 4);
    #pragma unroll
    for (int i = 0; i < 4; ++i) {
      const int r = i * 32 + srow;
      const int wslt = (sslt ^ (r & 7)) * 8;
      short8 pk;
      pk[0] = bf16bits(ra0[i].x); pk[1] = bf16bits(ra0[i].y);
      pk[2] = bf16bits(ra0[i].z); pk[3] = bf16bits(ra0[i].w);
      pk[4] = bf16bits(ra1[i].x); pk[5] = bf16bits(ra1[i].y);
      pk[6] = bf16bits(ra1[i].z); pk[7] = bf16bits(ra1[i].w);
      *reinterpret_cast<short8*>(&Ash[r * 64 + wslt]) = pk;
      short8 qk;
      qk[0] = bf16bits(rb0[i].x * w0.x); qk[1] = bf16bits(rb0[i].y * w0.y);
      qk[2] = bf16bits(rb0[i].z * w0.z); qk[3] = bf16bits(rb0[i].w * w0.w);
      qk[4] = bf16bits(rb1[i].x * w1.x); qk[5] = bf16bits(rb1[i].y * w1.y);
      qk[6] = bf16bits(rb1[i].z * w1.z); qk[7] = bf16bits(rb1[i].w * w1.w);
      *reinterpret_cast<short8*>(&Bsh[r * 64 + wslt]) = qk;
    }
    __syncthreads();
    if (ks < 9) {
      const int kn = (ks + 1) * 64 + sslt * 8;
      #pragma unroll
      for (int i = 0; i < 4; ++i) {
        const int r = i * 32 + srow;
        const float* sa = qb + (size_t)min(m0 + r, MM - 1) * DD + kn;
        ra0[i] = *reinterpret_cast<const float4*>(sa);
        ra1[i] = *reinterpret_cast<const float4*>(sa + 4);
        const float* sbp = sb + (size_t)min(n0 + r, KMM - 1) * DD + kn;
        rb0[i] = *reinterpret_cast<const float4*>(sbp);
        rb1[i] = *reinterpret_cast<const float4*>(sbp + 4);
      }
    }
    #pragma unroll
    for (int kk = 0; kk < 4; ++kk) {
      const int ph = ((kk * 2 + lh) ^ (l31 & 7)) * 8;
      short8 a0 = *reinterpret_cast<short8*>(&Ash[(wm * 64      + l31) * 64 + ph]);
      short8 a1 = *reinterpret_cast<short8*>(&Ash[(wm * 64 + 32 + l31) * 64 + ph]);
      short8 b0 = *reinterpret_cast<short8*>(&Bsh[(wn * 64      + l31) * 64 + ph]);
      short8 b1 = *reinterpret_cast<short8*>(&Bsh[(wn * 64 + 32 + l31) * 64 + ph]);
      acc[0][0] = __builtin_amdgcn_mfma_f32_32x32x16_bf16(a0, b0, acc[0][0], 0, 0, 0);
      acc[0][1] = __builtin_amdgcn_mfma_f32_32x32x16_bf16(a0, b1, acc[0][1], 0, 0, 0);
      acc[1][0] = __builtin_amdgcn_mfma_f32_32x32x16_bf16(a1, b0, acc[1][0], 0, 0, 0);
      acc[1][1] = __builtin_amdgcn_mfma_f32_32x32x16_bf16(a1, b1, acc[1][1], 0, 0, 0);
    }
    __syncthreads();
  }

  // epilogue: r = sim*C2 -> e4m3 store + colsum of 2^(dequantized r)
  unsigned char* cb = cost + (size_t)pair * (MM * KP);
  #pragma unroll
  for (int nt = 0; nt < 2; ++nt) {
    const int ncol = n0 + wn * 64 + nt * 32 + l31;
    float part = 0.f;
    #pragma unroll
    for (int mt = 0; mt < 2; ++mt) {
      #pragma unroll
      for (int r = 0; r < 16; ++r) {
        const int mrow = m0 + wm * 64 + mt * 32 + (r & 3) + 8 * (r >> 2) + 4 * lh;
        if (mrow < MM && ncol < KMM) {
          unsigned int enc = f32_to_e4m3(acc[mt][nt][r] * C2);
          cb[(size_t)mrow * KP + ncol] = (unsigned char)enc;
          part += EXP2F(e4m3_to_f32(enc));
        }
      }
    }
    atomicAdd(&cs_lds[wn * 64 + nt * 32 + l31], part);
  }
  __syncthreads();
  if (tid < 64) {
    const int c0 = n0 + 2 * tid;
    if (c0 < KMM)
      h2AtomicAdd(reinterpret_cast<__half2*>(T1 + (size_t)pair * KMM + c0),
                  cs_lds[2 * tid], cs_lds[2 * tid + 1]);
  }
}

// ---------------- fused sweep over fp8 cost: one pass per iteration ----------
// p = 2^r (r dequantized e4m3), iT = 1/(980*T) [= alpha*v, alpha cancels].
// A = sum_k p*iT -> up = 1/(196A) = 2^u. Non-FIN: T'[k] += p*up.
// FIN: row Sum(gamma*c) = Bv*up - C2/196 with Bv = sum e*r; out += /(C2*tau).
template<bool FIN>
__global__ __launch_bounds__(256)
void sweep_kernel(const unsigned char* __restrict__ cost, const __half* __restrict__ Tin,
                  __half* __restrict__ Tout, const float* __restrict__ epsr,
                  const float* __restrict__ taur, float* __restrict__ outp)
{
  __shared__ float part[4][1024];
  const int tid  = threadIdx.x;
  const int wave = tid >> 6;
  const int lane = tid & 63;
  const int pair   = blockIdx.x / 7;
  const int mchunk = blockIdx.x % 7;

  const unsigned char* cb = cost + (size_t)pair * (MM * KP);
  const __half* tp = Tin + (size_t)pair * KMM;

  const int k1 = 8 * lane;          // k1..k1+7   (<= 511, valid)
  const int k2 = 512 + 8 * lane;    // k2..k2+7   (mask >= 980; OOB reads masked)

  float iT[16];
  {
    uint2 ta = *reinterpret_cast<const uint2*>(tp + k1);
    uint2 tb = *reinterpret_cast<const uint2*>(tp + k1 + 4);
    uint2 tc = *reinterpret_cast<const uint2*>(tp + k2);
    uint2 td = *reinterpret_cast<const uint2*>(tp + k2 + 4);
    float2 f;
    f = __half22float2(*reinterpret_cast<const __half2*>(&ta.x)); iT[0] = RCPF(980.f * f.x); iT[1] = RCPF(980.f * f.y);
    f = __half22float2(*reinterpret_cast<const __half2*>(&ta.y)); iT[2] = RCPF(980.f * f.x); iT[3] = RCPF(980.f * f.y);
    f = __half22float2(*reinterpret_cast<const __half2*>(&tb.x)); iT[4] = RCPF(980.f * f.x); iT[5] = RCPF(980.f * f.y);
    f = __half22float2(*reinterpret_cast<const __half2*>(&tb.y)); iT[6] = RCPF(980.f * f.x); iT[7] = RCPF(980.f * f.y);
    f = __half22float2(*reinterpret_cast<const __half2*>(&tc.x)); iT[8] = RCPF(980.f * f.x); iT[9] = RCPF(980.f * f.y);
    f = __half22float2(*reinterpret_cast<const __half2*>(&tc.y)); iT[10] = RCPF(980.f * f.x); iT[11] = RCPF(980.f * f.y);
    f = __half22float2(*reinterpret_cast<const __half2*>(&td.x)); iT[12] = RCPF(980.f * f.x); iT[13] = RCPF(980.f * f.y);
    f = __half22float2(*reinterpret_cast<const __half2*>(&td.y)); iT[14] = RCPF(980.f * f.x); iT[15] = RCPF(980.f * f.y);
    #pragma unroll
    for (int e = 8; e < 16; ++e)
      if (k2 + (e - 8) >= KMM) iT[e] = 0.f;
  }

  float acc[16];
  #pragma unroll
  for (int e = 0; e < 16; ++e) acc[e] = 0.f;

  float scal = 0.f, c2f = 0.f, rowtot = 0.f;
  if (FIN) {
    const float eps = logf(1.0f + expf(epsr[0])) + 1e-4f;
    c2f = 1.4426950408889634f / eps;
    const float tau = logf(1.0f + expf(taur[0])) + 0.01f;
    scal = 1.0f / (tau * c2f);
  }

  #pragma unroll
  for (int r = 0; r < 7; ++r) {
    const int m = mchunk * 28 + wave * 7 + r;
    const unsigned char* rp = cb + (size_t)m * KP;
    uint2 w1 = *reinterpret_cast<const uint2*>(rp + k1);
    uint2 w2 = *reinterpret_cast<const uint2*>(rp + k2);
    float r_[16], p_[16];
    #pragma unroll
    for (int e = 0; e < 4; ++e) {
      r_[e]      = dec8(w1.x, e);
      r_[4 + e]  = dec8(w1.y, e);
      r_[8 + e]  = dec8(w2.x, e);
      r_[12 + e] = dec8(w2.y, e);
    }
    #pragma unroll
    for (int e = 0; e < 16; ++e) p_[e] = EXP2F(r_[e]);
    #pragma unroll
    for (int e = 8; e < 16; ++e)
      if (k2 + (e - 8) >= KMM) p_[e] = 0.f;

    float A = 0.f, Bv = 0.f;
    #pragma unroll
    for (int e = 0; e < 16; ++e) {
      float ee = p_[e] * iT[e];
      A += ee;
      if (FIN) Bv += ee * r_[e];
    }
    #pragma unroll
    for (int s = 32; s; s >>= 1) {
      A += __shfl_xor(A, s);
      if (FIN) Bv += __shfl_xor(Bv, s);
    }
    const float up = RCPF(196.0f * A);        // = 2^{u_new}
    if (FIN) {
      rowtot += Bv * up - c2f * (1.0f / 196.0f);
    } else {
      #pragma unroll
      for (int e = 0; e < 16; ++e) acc[e] += p_[e] * up;
    }
  }

  if (FIN) {
    if (lane == 0) {
      const int opair = (pair % 50) * NWAY + (pair / 50);   // way-major -> [q,way]
      atomicAdd(outp + opair, rowtot * scal);
    }
  } else {
    #pragma unroll
    for (int e = 0; e < 8; ++e) part[wave][k1 + e] = acc[e];
    #pragma unroll
    for (int e = 0; e < 8; ++e) part[wave][k2 + e] = acc[8 + e];
    __syncthreads();
    __half* top = Tout + (size_t)pair * KMM;
    for (int c2c = tid; c2c < KMM / 2; c2c += 256) {
      const int c = 2 * c2c;
      float s0 = part[0][c]     + part[1][c]     + part[2][c]     + part[3][c];
      float s1 = part[0][c + 1] + part[1][c + 1] + part[2][c + 1] + part[3][c + 1];
      h2AtomicAdd(reinterpret_cast<__half2*>(top + c), s0, s1);
    }
  }
}

extern "C" void kernel_launch(void* const* d_in, const int* in_sizes, int n_in,
                              void* d_out, int out_size, void* d_ws, size_t ws_size,
                              hipStream_t stream) {
  const float* qt  = (const float*)d_in[0];
  const float* st  = (const float*)d_in[1];
  const float* var = (const float*)d_in[2];
  const float* er  = (const float*)d_in[3];
  const float* tr  = (const float*)d_in[4];
  float* out = (float*)d_out;

  // ws layout (49,196,000 B, well under proven 97,216,000 budget):
  //   cost e4m3 : 250*196*984 = 48,216,000
  //   Ta   fp16 : 250*980*2   =    490,000
  //   Tb   fp16 : 250*980*2   =    490,000
  char* ws = (char*)d_ws;
  unsigned char* cost = (unsigned char*)ws;
  __half* Ta = (__half*)(ws + 48216000);
  __half* Tb = (__half*)(ws + 48216000 + 490000);

  (void)hipMemsetAsync(out, 0, NPAIR * sizeof(float), stream);
  (void)hipMemsetAsync(Ta, 0, (size_t)NPAIR * KMM * sizeof(__half), stream);

  gemm_kernel<<<NPAIR * 16, 256, 0, stream>>>(qt, st, var, er, cost, Ta);

  __half* cur = Ta;
  __half* nxt = Tb;
  for (int it = 0; it < NITER - 1; ++it) {
    (void)hipMemsetAsync(nxt, 0, (size_t)NPAIR * KMM * sizeof(__half), stream);
    sweep_kernel<false><<<NPAIR * 7, 256, 0, stream>>>(cost, cur, nxt, er, tr, out);
    __half* t = cur; cur = nxt; nxt = t;
  }
  sweep_kernel<true><<<NPAIR * 7, 256, 0, stream>>>(cost, cur, nullptr, er, tr, out);
}

// Round 11
// 360.552 us; speedup vs baseline: 2.4765x; 1.0874x over previous
//
#include <hip/hip_runtime.h>
#include <hip/hip_bf16.h>
#include <hip/hip_fp16.h>

#define QN    50
#define NWAY  5
#define NPAIR 250
#define MM    196
#define KMM   980
#define KP    984     // fp8 cost row stride (8B aligned)
#define DD    640
#define NITER 5

typedef __attribute__((ext_vector_type(8)))  short short8;
typedef __attribute__((ext_vector_type(16))) float f32x16;

#define EXP2F(x) __builtin_exp2f(x)
#define RCPF(x)  __builtin_amdgcn_rcpf(x)

#define E4M3_UP 1.3292279957849159e36f   // 2^120
#define E4M3_DN 7.5231638452626401e-37f  // 2^-120

__device__ __forceinline__ short bf16bits(float f) {
  __hip_bfloat16 h = __float2bfloat16(f);
  return *reinterpret_cast<short*>(&h);
}

// e4m3 encode: clamp to 448, scale into f32 bit-domain, round mantissa.
// Decode below is the exact bit-inverse — this PAIR is what was verified
// at absmax 0.0 (round 9). HW cvt_pk_f32_fp8 NaN'd (round 10) — do not use.
__device__ __forceinline__ unsigned int f32_to_e4m3(float x) {
  unsigned int b = __float_as_uint(x);
  unsigned int sgn = (b >> 24) & 0x80u;
  float a = __uint_as_float(b & 0x7FFFFFFFu);
  a = fminf(a, 448.0f);
  unsigned int z = __float_as_uint(a * E4M3_DN);
  unsigned int mag = (z + 0x00080000u) >> 20;   // round-half-up; max 0x7E
  return sgn | mag;
}
__device__ __forceinline__ float e4m3_to_f32(unsigned int v) {
  return __uint_as_float(((v & 0x80u) << 24) | ((v & 0x7Fu) << 20)) * E4M3_UP;
}
__device__ __forceinline__ void dec4(unsigned int w, float* out) {
  out[0] = e4m3_to_f32(w & 0xFFu);
  out[1] = e4m3_to_f32((w >> 8) & 0xFFu);
  out[2] = e4m3_to_f32((w >> 16) & 0xFFu);
  out[3] = e4m3_to_f32((w >> 24) & 0xFFu);
}

// packed-half2 atomic add via CAS (no atomicAdd(__half2*) overload in ROCm7)
__device__ __forceinline__ void h2AtomicAdd(__half2* addr, float a, float b) {
  unsigned int* ui = reinterpret_cast<unsigned int*>(addr);
  unsigned int old = __hip_atomic_load(ui, __ATOMIC_RELAXED, __HIP_MEMORY_SCOPE_AGENT);
  unsigned int assumed;
  do {
    assumed = old;
    __half2 cur = *reinterpret_cast<__half2*>(&assumed);
    float2 cf = __half22float2(cur);
    __half2 sum = __floats2half2_rn(cf.x + a, cf.y + b);
    unsigned int ns = *reinterpret_cast<unsigned int*>(&sum);
    old = atomicCAS(ui, assumed, ns);
  } while (old != assumed);
}

// ---------------- prep 1: per-way dimension weights w = inv/(sum inv)*D ------
__global__ __launch_bounds__(256)
void prep_w(const float* __restrict__ var, float* __restrict__ wbuf)
{
  __shared__ float red[4];
  const int way = blockIdx.x, tid = threadIdx.x;
  float s = 0.f;
  for (int d = tid; d < DD; d += 256) s += 1.0f / (var[way * DD + d] + 0.01f);
  #pragma unroll
  for (int sh = 32; sh; sh >>= 1) s += __shfl_xor(s, sh);
  if ((tid & 63) == 0) red[tid >> 6] = s;
  __syncthreads();
  const float tot = red[0] + red[1] + red[2] + red[3];
  const float sc  = (float)DD / fmaxf(tot, 1e-6f);
  for (int d = tid; d < DD; d += 256)
    wbuf[way * DD + d] = sc / (var[way * DD + d] + 0.01f);
}

// ---------------- prep 2: q -> bf16 ; s*w -> bf16 (one 8-elem unit/thread) ---
#define QUNITS 784000              // 50*196*640/8
#define TUNITS 1176000             // + 5*980*640/8
__global__ __launch_bounds__(256)
void prep_cvt(const float* __restrict__ qt, const float* __restrict__ st,
              const float* __restrict__ wbuf,
              unsigned short* __restrict__ qb16, unsigned short* __restrict__ sw16)
{
  const size_t u = (size_t)blockIdx.x * 256 + threadIdx.x;
  if (u >= TUNITS) return;
  short8 o;
  if (u < QUNITS) {
    const float* src = qt + u * 8;
    float4 f0 = *reinterpret_cast<const float4*>(src);
    float4 f1 = *reinterpret_cast<const float4*>(src + 4);
    o[0] = bf16bits(f0.x); o[1] = bf16bits(f0.y); o[2] = bf16bits(f0.z); o[3] = bf16bits(f0.w);
    o[4] = bf16bits(f1.x); o[5] = bf16bits(f1.y); o[6] = bf16bits(f1.z); o[7] = bf16bits(f1.w);
    *reinterpret_cast<short8*>(qb16 + u * 8) = o;
  } else {
    const size_t e = (u - QUNITS) * 8;         // linear over [way][980][640]
    const int d0 = (int)(e % DD);
    const int way = (int)(e / ((size_t)KMM * DD));
    const float* src = st + e;
    const float* wp  = wbuf + way * DD + d0;
    float4 f0 = *reinterpret_cast<const float4*>(src);
    float4 f1 = *reinterpret_cast<const float4*>(src + 4);
    float4 w0 = *reinterpret_cast<const float4*>(wp);
    float4 w1 = *reinterpret_cast<const float4*>(wp + 4);
    o[0] = bf16bits(f0.x * w0.x); o[1] = bf16bits(f0.y * w0.y);
    o[2] = bf16bits(f0.z * w0.z); o[3] = bf16bits(f0.w * w0.w);
    o[4] = bf16bits(f1.x * w1.x); o[5] = bf16bits(f1.y * w1.y);
    o[6] = bf16bits(f1.z * w1.z); o[7] = bf16bits(f1.w * w1.w);
    *reinterpret_cast<short8*>(sw16 + e) = o;
  }
}

// ---------------- tiled GEMM on bf16 inputs: cost = e4m3(sim*C2) + colsum ----
// 128x128 tile, BK=64, 4 waves 2x2 of 64x64, LDS XOR-swizzle, 2-phase register
// prefetch (pure short8 moves - zero conversion VALU). Way-major + XCD chunk.
__global__ __launch_bounds__(256, 4)
void gemm_kernel(const unsigned short* __restrict__ qb16,
                 const unsigned short* __restrict__ sw16,
                 const float* __restrict__ epsr,
                 unsigned char* __restrict__ cost, __half* __restrict__ T1)
{
  __shared__ __align__(16) unsigned short Ash[128 * 64];
  __shared__ __align__(16) unsigned short Bsh[128 * 64];
  __shared__ float cs_lds[128];

  const int tid  = threadIdx.x;
  const int wv   = tid >> 6;
  const int lane = tid & 63;
  const int l31  = lane & 31;
  const int lh   = lane >> 5;
  const int wm   = wv >> 1;
  const int wn   = wv & 1;

  const int lg   = (blockIdx.x & 7) * 500 + (blockIdx.x >> 3);
  const int pair = lg >> 4;
  const int mt_  = (lg >> 3) & 1;
  const int nt_  = lg & 7;
  const int wi = pair / 50, qi = pair % 50;     // way-major
  const int m0 = mt_ * 128, n0 = nt_ * 128;

  const float eps = logf(1.0f + expf(epsr[0])) + 1e-4f;
  const float C2  = 1.4426950408889634f / eps;

  const unsigned short* qb = qb16 + (size_t)qi * MM * DD;
  const unsigned short* sb = sw16 + (size_t)wi * KMM * DD;

  f32x16 acc[2][2];
  #pragma unroll
  for (int i = 0; i < 2; ++i)
    #pragma unroll
    for (int j = 0; j < 2; ++j)
      #pragma unroll
      for (int e = 0; e < 16; ++e) acc[i][j][e] = 0.f;

  const int srow = tid >> 3;
  const int sslt = tid & 7;

  short8 pa[4], pb[4];
  #pragma unroll
  for (int i = 0; i < 4; ++i) {
    const int r = i * 32 + srow;
    pa[i] = *reinterpret_cast<const short8*>(qb + (size_t)min(m0 + r, MM - 1) * DD + sslt * 8);
    pb[i] = *reinterpret_cast<const short8*>(sb + (size_t)min(n0 + r, KMM - 1) * DD + sslt * 8);
  }
  if (tid < 128) cs_lds[tid] = 0.f;

  #pragma unroll
  for (int ks = 0; ks < 10; ++ks) {
    #pragma unroll
    for (int i = 0; i < 4; ++i) {
      const int r = i * 32 + srow;
      const int wslt = (sslt ^ (r & 7)) * 8;
      *reinterpret_cast<short8*>(&Ash[r * 64 + wslt]) = pa[i];
      *reinterpret_cast<short8*>(&Bsh[r * 64 + wslt]) = pb[i];
    }
    __syncthreads();
    if (ks < 9) {
      const int kn = (ks + 1) * 64 + sslt * 8;
      #pragma unroll
      for (int i = 0; i < 4; ++i) {
        const int r = i * 32 + srow;
        pa[i] = *reinterpret_cast<const short8*>(qb + (size_t)min(m0 + r, MM - 1) * DD + kn);
        pb[i] = *reinterpret_cast<const short8*>(sb + (size_t)min(n0 + r, KMM - 1) * DD + kn);
      }
    }
    #pragma unroll
    for (int kk = 0; kk < 4; ++kk) {
      const int ph = ((kk * 2 + lh) ^ (l31 & 7)) * 8;
      short8 a0 = *reinterpret_cast<short8*>(&Ash[(wm * 64      + l31) * 64 + ph]);
      short8 a1 = *reinterpret_cast<short8*>(&Ash[(wm * 64 + 32 + l31) * 64 + ph]);
      short8 b0 = *reinterpret_cast<short8*>(&Bsh[(wn * 64      + l31) * 64 + ph]);
      short8 b1 = *reinterpret_cast<short8*>(&Bsh[(wn * 64 + 32 + l31) * 64 + ph]);
      acc[0][0] = __builtin_amdgcn_mfma_f32_32x32x16_bf16(a0, b0, acc[0][0], 0, 0, 0);
      acc[0][1] = __builtin_amdgcn_mfma_f32_32x32x16_bf16(a0, b1, acc[0][1], 0, 0, 0);
      acc[1][0] = __builtin_amdgcn_mfma_f32_32x32x16_bf16(a1, b0, acc[1][0], 0, 0, 0);
      acc[1][1] = __builtin_amdgcn_mfma_f32_32x32x16_bf16(a1, b1, acc[1][1], 0, 0, 0);
    }
    __syncthreads();
  }

  // epilogue: r = sim*C2 -> e4m3 store + colsum of 2^(decoded r) (u0 = 0)
  unsigned char* cb = cost + (size_t)pair * (MM * KP);
  #pragma unroll
  for (int nt = 0; nt < 2; ++nt) {
    const int ncol = n0 + wn * 64 + nt * 32 + l31;
    float part = 0.f;
    #pragma unroll
    for (int r = 0; r < 16; ++r) {
      const int mrow = m0 + wm * 64 + (r & 3) + 8 * (r >> 2) + 4 * lh;
      if (mrow < MM && ncol < KMM) {
        unsigned int enc = f32_to_e4m3(acc[0][nt][r] * C2);
        cb[(size_t)mrow * KP + ncol] = (unsigned char)enc;
        part += EXP2F(e4m3_to_f32(enc));
      }
      const int mrow2 = mrow + 32;
      if (mrow2 < MM && ncol < KMM) {
        unsigned int enc = f32_to_e4m3(acc[1][nt][r] * C2);
        cb[(size_t)mrow2 * KP + ncol] = (unsigned char)enc;
        part += EXP2F(e4m3_to_f32(enc));
      }
    }
    atomicAdd(&cs_lds[wn * 64 + nt * 32 + l31], part);
  }
  __syncthreads();
  if (tid < 64) {
    const int c0 = n0 + 2 * tid;
    if (c0 < KMM)
      h2AtomicAdd(reinterpret_cast<__half2*>(T1 + (size_t)pair * KMM + c0),
                  cs_lds[2 * tid], cs_lds[2 * tid + 1]);
  }
}

// ---------------- fused sweep over fp8 cost: one pass per iteration ----------
template<bool FIN>
__global__ __launch_bounds__(256)
void sweep_kernel(const unsigned char* __restrict__ cost, const __half* __restrict__ Tin,
                  __half* __restrict__ Tout, const float* __restrict__ epsr,
                  const float* __restrict__ taur, float* __restrict__ outp)
{
  __shared__ float part[4][1024];
  const int tid  = threadIdx.x;
  const int wave = tid >> 6;
  const int lane = tid & 63;
  const int pair   = blockIdx.x / 7;
  const int mchunk = blockIdx.x % 7;

  const unsigned char* cb = cost + (size_t)pair * (MM * KP);
  const __half* tp = Tin + (size_t)pair * KMM;

  const int k1 = 8 * lane;          // k1..k1+7   (<= 511, valid)
  const int k2 = 512 + 8 * lane;    // k2..k2+7   (mask >= 980)

  float iT[16];
  {
    uint2 ta = *reinterpret_cast<const uint2*>(tp + k1);
    uint2 tb = *reinterpret_cast<const uint2*>(tp + k1 + 4);
    uint2 tc = *reinterpret_cast<const uint2*>(tp + k2);
    uint2 td = *reinterpret_cast<const uint2*>(tp + k2 + 4);
    float2 f;
    f = __half22float2(*reinterpret_cast<const __half2*>(&ta.x)); iT[0]  = RCPF(980.f * f.x); iT[1]  = RCPF(980.f * f.y);
    f = __half22float2(*reinterpret_cast<const __half2*>(&ta.y)); iT[2]  = RCPF(980.f * f.x); iT[3]  = RCPF(980.f * f.y);
    f = __half22float2(*reinterpret_cast<const __half2*>(&tb.x)); iT[4]  = RCPF(980.f * f.x); iT[5]  = RCPF(980.f * f.y);
    f = __half22float2(*reinterpret_cast<const __half2*>(&tb.y)); iT[6]  = RCPF(980.f * f.x); iT[7]  = RCPF(980.f * f.y);
    f = __half22float2(*reinterpret_cast<const __half2*>(&tc.x)); iT[8]  = RCPF(980.f * f.x); iT[9]  = RCPF(980.f * f.y);
    f = __half22float2(*reinterpret_cast<const __half2*>(&tc.y)); iT[10] = RCPF(980.f * f.x); iT[11] = RCPF(980.f * f.y);
    f = __half22float2(*reinterpret_cast<const __half2*>(&td.x)); iT[12] = RCPF(980.f * f.x); iT[13] = RCPF(980.f * f.y);
    f = __half22float2(*reinterpret_cast<const __half2*>(&td.y)); iT[14] = RCPF(980.f * f.x); iT[15] = RCPF(980.f * f.y);
    #pragma unroll
    for (int e = 8; e < 16; ++e)
      if (k2 + (e - 8) >= KMM) iT[e] = 0.f;
  }

  float acc[16];
  #pragma unroll
  for (int e = 0; e < 16; ++e) acc[e] = 0.f;

  float scal = 0.f, c2f = 0.f, rowtot = 0.f;
  if (FIN) {
    const float eps = logf(1.0f + expf(epsr[0])) + 1e-4f;
    c2f = 1.4426950408889634f / eps;
    const float tau = logf(1.0f + expf(taur[0])) + 0.01f;
    scal = 1.0f / (tau * c2f);
  }

  #pragma unroll
  for (int r = 0; r < 7; ++r) {
    const int m = mchunk * 28 + wave * 7 + r;
    const unsigned char* rp = cb + (size_t)m * KP;
    uint2 w1 = *reinterpret_cast<const uint2*>(rp + k1);
    uint2 w2 = *reinterpret_cast<const uint2*>(rp + k2);
    float r_[16], p_[16];
    dec4(w1.x, r_ + 0);  dec4(w1.y, r_ + 4);
    dec4(w2.x, r_ + 8);  dec4(w2.y, r_ + 12);
    #pragma unroll
    for (int e = 0; e < 16; ++e) p_[e] = EXP2F(r_[e]);
    #pragma unroll
    for (int e = 8; e < 16; ++e)
      if (k2 + (e - 8) >= KMM) p_[e] = 0.f;

    float A = 0.f, Bv = 0.f;
    #pragma unroll
    for (int e = 0; e < 16; ++e) {
      float ee = p_[e] * iT[e];
      A += ee;
      if (FIN) Bv += ee * r_[e];
    }
    #pragma unroll
    for (int s = 32; s; s >>= 1) {
      A += __shfl_xor(A, s);
      if (FIN) Bv += __shfl_xor(Bv, s);
    }
    const float up = RCPF(196.0f * A);        // = 2^{u_new}
    if (FIN) {
      rowtot += Bv * up - c2f * (1.0f / 196.0f);
    } else {
      #pragma unroll
      for (int e = 0; e < 16; ++e) acc[e] += p_[e] * up;
    }
  }

  if (FIN) {
    if (lane == 0) {
      const int opair = (pair % 50) * NWAY + (pair / 50);   // way-major -> [q,way]
      atomicAdd(outp + opair, rowtot * scal);
    }
  } else {
    #pragma unroll
    for (int e = 0; e < 8; ++e) part[wave][k1 + e] = acc[e];
    #pragma unroll
    for (int e = 0; e < 8; ++e) part[wave][k2 + e] = acc[8 + e];
    __syncthreads();
    __half* top = Tout + (size_t)pair * KMM;
    for (int c2c = tid; c2c < KMM / 2; c2c += 256) {
      const int c = 2 * c2c;
      float s0 = part[0][c]     + part[1][c]     + part[2][c]     + part[3][c];
      float s1 = part[0][c + 1] + part[1][c + 1] + part[2][c + 1] + part[3][c + 1];
      h2AtomicAdd(reinterpret_cast<__half2*>(top + c), s0, s1);
    }
  }
}

extern "C" void kernel_launch(void* const* d_in, const int* in_sizes, int n_in,
                              void* d_out, int out_size, void* d_ws, size_t ws_size,
                              hipStream_t stream) {
  const float* qt  = (const float*)d_in[0];
  const float* st  = (const float*)d_in[1];
  const float* var = (const float*)d_in[2];
  const float* er  = (const float*)d_in[3];
  const float* tr  = (const float*)d_in[4];
  float* out = (float*)d_out;

  // ws layout (68,024,800 B <= proven 97,216,000 budget):
  //   cost e4m3 : 250*196*984       = 48,216,000   @ 0
  //   Ta   fp16 : 250*980*2         =    490,000   @ 48,216,000
  //   Tb   fp16 : 250*980*2         =    490,000   @ 48,706,000
  //   wbuf f32  : 5*640*4           =     12,800   @ 49,196,000
  //   qb16 bf16 : 50*196*640*2      = 12,544,000   @ 49,208,800
  //   sw16 bf16 : 5*980*640*2       =  6,272,000   @ 61,752,800
  char* ws = (char*)d_ws;
  unsigned char* cost = (unsigned char*)ws;
  __half* Ta = (__half*)(ws + 48216000);
  __half* Tb = (__half*)(ws + 48706000);
  float* wbuf = (float*)(ws + 49196000);
  unsigned short* qb16 = (unsigned short*)(ws + 49208800);
  unsigned short* sw16 = (unsigned short*)(ws + 61752800);

  (void)hipMemsetAsync(out, 0, NPAIR * sizeof(float), stream);
  (void)hipMemsetAsync(Ta, 0, (size_t)NPAIR * KMM * sizeof(__half), stream);

  prep_w<<<NWAY, 256, 0, stream>>>(var, wbuf);
  prep_cvt<<<(TUNITS + 255) / 256, 256, 0, stream>>>(qt, st, wbuf, qb16, sw16);
  gemm_kernel<<<NPAIR * 16, 256, 0, stream>>>(qb16, sw16, er, cost, Ta);

  __half* cur = Ta;
  __half* nxt = Tb;
  for (int it = 0; it < NITER - 1; ++it) {
    (void)hipMemsetAsync(nxt, 0, (size_t)NPAIR * KMM * sizeof(__half), stream);
    sweep_kernel<false><<<NPAIR * 7, 256, 0, stream>>>(cost, cur, nxt, er, tr, out);
    __half* t = cur; cur = nxt; nxt = t;
  }
  sweep_kernel<true><<<NPAIR * 7, 256, 0, stream>>>(cost, cur, nullptr, er, tr, out);
}